// Round 11
// baseline (996.313 us; speedup 1.0000x reference)
//
#include <hip/hip_runtime.h>
#include <hip/hip_bf16.h>

constexpr int B_ = 2, H_ = 256, W_ = 1216;
constexpr int HW = H_ * W_;          // 311296
constexpr int NP = B_ * HW;          // 622592
constexpr int WP = W_ + 2;           // 1218 padded width
constexpr int HP = H_ + 2;           // 258  padded height
constexpr int HWP = HP * WP;         // 314244
constexpr float EPS_ = 1e-6f;

// prepped-weight region offsets (ushort units)
constexpr int PW1_K3 = 0;                    // [2][9][32][32] hi/lo
constexpr int PW1_K5 = 18432;
constexpr int PW1_K7 = 36864;
constexpr int PW2_K3 = 55296;                // [2][9][16][32]
constexpr int PW2_K5 = 64512;                // [2][9][32][32]
constexpr int PW2_K7 = 82944;                // [2][9][48][32]
constexpr int PP1_M  = 110592;               // [9][32][32] plain
constexpr int PP1_C  = 119808;
constexpr int PP1_T  = 129024;
constexpr int PP1T2  = 138240;               // [9][32][8]
constexpr int PG2_M  = 140544;               // [9][16][32] plain
constexpr int PG2_C  = 145152;
constexpr int PG2_T  = 149760;
constexpr int PREP_N = 154368;

typedef __bf16 bfrag __attribute__((ext_vector_type(8)));
typedef float f4 __attribute__((ext_vector_type(4)));

union BU { uint4 u; bfrag f; };
union U8 { uint4 u; ushort s[8]; };

__device__ __forceinline__ ushort f2b(float x) {
  uint u = __float_as_uint(x);
  u += 0x7fffu + ((u >> 16) & 1u);
  return (ushort)(u >> 16);
}
__device__ __forceinline__ float b2f(ushort u) {
  return __uint_as_float(((uint)u) << 16);
}

// ---------------------------------------------------------------------------
// One-shot weight prep: OIHW fp32 -> fragment-ready bf16 layouts.
// ---------------------------------------------------------------------------
__global__ __launch_bounds__(256)
void prep_k(const float* __restrict__ k3w1, const float* __restrict__ k5w1,
            const float* __restrict__ k7w1, const float* __restrict__ k3w2,
            const float* __restrict__ k5w2, const float* __restrict__ k7w2,
            const float* __restrict__ mw1, const float* __restrict__ cw1,
            const float* __restrict__ tw1, const float* __restrict__ mw2,
            const float* __restrict__ cw2, const float* __restrict__ tw2,
            ushort* __restrict__ wp)
{
  int i = blockIdx.x * 256 + threadIdx.x;
  if (i >= PREP_N) return;
  ushort outv;
  if (i < PW2_K3) {                       // conv1 chains hi/lo [c][2][9][32][32]
    int c = i / 18432, r = i % 18432;
    const float* src = (c == 0) ? k3w1 : (c == 1) ? k5w1 : k7w1;
    int ci = r & 31; int t1 = r >> 5;
    int co = t1 & 31; int t2 = t1 >> 5;
    int tap = t2 % 9, half = t2 / 9;
    float v = src[(co * 32 + ci) * 9 + tap];
    ushort hi = f2b(v);
    outv = half ? f2b(v - b2f(hi)) : hi;
  } else if (i < PP1_M) {                 // conv2 chains [2][9][NM16][32]
    int r = i - PW2_K3;
    const float* src; int NM16, CO;
    if (r < 9216)       { src = k3w2; NM16 = 16; CO = 8; }
    else if (r < 27648) { src = k5w2; NM16 = 32; CO = 24; r -= 9216; }
    else                { src = k7w2; NM16 = 48; CO = 48; r -= 27648; }
    int ci = r & 31; int t1 = r >> 5;
    int co = t1 % NM16; int t2 = t1 / NM16;
    int tap = t2 % 9, half = t2 / 9;
    if (co < CO) {
      float v = src[(co * 32 + ci) * 9 + tap];
      ushort hi = f2b(v);
      outv = half ? f2b(v - b2f(hi)) : hi;
    } else outv = 0;
  } else if (i < PP1T2) {                 // conv1p plain [c][9][32][32]
    int r = i - PP1_M;
    int c = r / 9216; r %= 9216;
    const float* src = (c == 0) ? mw1 : (c == 1) ? cw1 : tw1;
    int CIN = (c == 2) ? 35 : 32;
    int ci = r & 31; int t1 = r >> 5;
    int co = t1 & 31, tap = t1 >> 5;
    outv = f2b(src[(co * CIN + ci) * 9 + tap]);
  } else if (i < PG2_M) {                 // t-branch extra K [9][32][8]
    int r = i - PP1T2;
    int c8 = r & 7; int t1 = r >> 3;
    int co = t1 & 31, tap = t1 >> 5;
    int cc = (c8 < 3) ? c8 : ((c8 < 6) ? c8 - 3 : -1);
    outv = (cc >= 0) ? f2b(tw1[(co * 35 + 32 + cc) * 9 + tap]) : (ushort)0;
  } else {                                // conv2g [c][9][16][32]
    int r = i - PG2_M;
    int c = r / 4608; r %= 4608;
    const float* src = (c == 0) ? mw2 : (c == 1) ? cw2 : tw2;
    int ci = r & 31; int t1 = r >> 5;
    int co = t1 & 15, tap = t1 >> 4;
    outv = (co < 3) ? f2b(src[(co * 32 + ci) * 9 + tap]) : (ushort)0;
  }
  wp[i] = outv;
}

// ---------------------------------------------------------------------------
// Zero the pad ring of hP (padded NHWC bf16 [b][HP][WP][32]).
// ---------------------------------------------------------------------------
__global__ __launch_bounds__(256)
void zring_k(ushort* __restrict__ hP) {
  constexpr int PB = 2 * WP * 4 + 2 * (HP - 2) * 4;   // uint4 units per batch
  int i = blockIdx.x * 256 + threadIdx.x;
  if (i >= 2 * PB) return;
  int b = i / PB, r = i % PB;
  size_t idx;
  if (r < WP * 4) idx = (size_t)r;
  else if (r < 2 * WP * 4) idx = (size_t)(HP - 1) * WP * 4 + (r - WP * 4);
  else {
    int q = r - 2 * WP * 4;
    int row = q >> 3, k = q & 7;
    int col = (k < 4) ? k : (WP - 1) * 4 + (k - 4);
    idx = (size_t)(row + 1) * WP * 4 + col;
  }
  *(uint4*)&hP[(size_t)b * HWP * 32 + idx * 8] = uint4{0, 0, 0, 0};
}

// ---------------------------------------------------------------------------
// Split-precision conv1 (w-chains), 512 threads (8 waves): latency-bound at
// 3 blocks/CU (50.7KB LDS) -> double waves/CU vs 256-thread version.
// Each wave handles tu=0..1, t = wid + tu*8.
// ---------------------------------------------------------------------------
__global__ __launch_bounds__(512, 4)
void convs1(const float* __restrict__ xf, const ushort* __restrict__ wp,
            const float* __restrict__ scale, const float* __restrict__ bias,
            ushort* __restrict__ outh)
{
  __shared__ ushort xl[25344];   // hi [0,12672) | lo [12672,25344)

  const int tid = threadIdx.x;
  const int lane = tid & 63;
  const int wid = tid >> 6;      // 0..7
  const int x0 = blockIdx.x * 64, y0 = blockIdx.y * 4, b = blockIdx.z;

  for (int i = tid; i < 396 * 4; i += 512) {
    int oct = i & 3, rest = i >> 2;
    int xx = rest % 66, rr = rest / 66;
    int yy = y0 - 1 + rr, x = x0 - 1 + xx;
    uint4 vh = {0, 0, 0, 0}, vl = {0, 0, 0, 0};
    if ((unsigned)yy < (unsigned)H_ && (unsigned)x < (unsigned)W_) {
      const float* src = xf + ((size_t)b * 32 + oct * 8) * HW + (size_t)yy * W_ + x;
      uint uh[4], ul[4];
#pragma unroll
      for (int j = 0; j < 4; ++j) {
        float a = src[(size_t)(2 * j + 0) * HW];
        float c = src[(size_t)(2 * j + 1) * HW];
        ushort ah = f2b(a), ch = f2b(c);
        ushort al = f2b(a - b2f(ah)), cl = f2b(c - b2f(ch));
        uh[j] = (uint)ah | ((uint)ch << 16);
        ul[j] = (uint)al | ((uint)cl << 16);
      }
      vh = uint4{uh[0], uh[1], uh[2], uh[3]};
      vl = uint4{ul[0], ul[1], ul[2], ul[3]};
    }
    *(uint4*)&xl[rest * 32 + oct * 8] = vh;
    *(uint4*)&xl[12672 + rest * 32 + oct * 8] = vl;
  }
  __syncthreads();

  const int n = lane & 15, quad = lane >> 4;

  f4 acc[2][2];
#pragma unroll
  for (int tu = 0; tu < 2; ++tu)
#pragma unroll
    for (int mt = 0; mt < 2; ++mt) acc[tu][mt] = f4{0.f, 0.f, 0.f, 0.f};

#pragma unroll
  for (int tap = 0; tap < 9; ++tap) {
    int dy = tap / 3, dx = tap % 3;
    bfrag avhi[2], avlo[2];
#pragma unroll
    for (int mt = 0; mt < 2; ++mt) {
      avhi[mt] = *(const bfrag*)&wp[((tap * 32) + mt * 16 + n) * 32 + quad * 8];
      avlo[mt] = *(const bfrag*)&wp[(((9 + tap) * 32) + mt * 16 + n) * 32 + quad * 8];
    }
#pragma unroll
    for (int tu = 0; tu < 2; ++tu) {
      int t = wid + tu * 8;
      int r = t >> 2, g = t & 3;
      int pix = (r + dy) * 66 + g * 16 + n + dx;
      bfrag bhi = *(const bfrag*)&xl[pix * 32 + quad * 8];
      bfrag blo = *(const bfrag*)&xl[12672 + pix * 32 + quad * 8];
#pragma unroll
      for (int mt = 0; mt < 2; ++mt) {
        acc[tu][mt] = __builtin_amdgcn_mfma_f32_16x16x32_bf16(avhi[mt], bhi, acc[tu][mt], 0, 0, 0);
        acc[tu][mt] = __builtin_amdgcn_mfma_f32_16x16x32_bf16(avhi[mt], blo, acc[tu][mt], 0, 0, 0);
        acc[tu][mt] = __builtin_amdgcn_mfma_f32_16x16x32_bf16(avlo[mt], bhi, acc[tu][mt], 0, 0, 0);
      }
    }
  }

#pragma unroll
  for (int tu = 0; tu < 2; ++tu) {
    int t = wid + tu * 8;
    int r = t >> 2, g = t & 3;
    int gx = x0 + g * 16 + n, gy = y0 + r;
    size_t bpix = (size_t)b * HWP + (size_t)(gy + 1) * WP + (gx + 1);
#pragma unroll
    for (int mt = 0; mt < 2; ++mt) {
      int cob = mt * 16 + quad * 4;
      float v0 = fmaxf(acc[tu][mt][0] * scale[cob + 0] + bias[cob + 0], 0.f);
      float v1 = fmaxf(acc[tu][mt][1] * scale[cob + 1] + bias[cob + 1], 0.f);
      float v2 = fmaxf(acc[tu][mt][2] * scale[cob + 2] + bias[cob + 2], 0.f);
      float v3 = fmaxf(acc[tu][mt][3] * scale[cob + 3] + bias[cob + 3], 0.f);
      uint u0 = (uint)f2b(v0) | ((uint)f2b(v1) << 16);
      uint u1 = (uint)f2b(v2) | ((uint)f2b(v3) << 16);
      *(uint2*)&outh[bpix * 32 + cob] = uint2{u0, u1};
    }
  }
}

// ---------------------------------------------------------------------------
// Split-precision conv2 (w-chains), 512 threads. LDS-staged B tile,
// tap-double-buffered weights, pixel-major packed output [B][HW][CO].
// ---------------------------------------------------------------------------
template<int nM, int MINW>
__global__ __launch_bounds__(512, MINW)
void convs2(const ushort* __restrict__ hP, const ushort* __restrict__ wp,
            const float* __restrict__ scale, const float* __restrict__ bias,
            ushort* __restrict__ outw, int CO)
{
  __shared__ ushort xl[12672];   // 6 rows x 66 px x 32 ch bf16 = 25344 B

  constexpr int NM16 = nM * 16;
  const int tid = threadIdx.x;
  const int lane = tid & 63;
  const int wid = tid >> 6;      // 0..7
  const int x0 = blockIdx.x * 64, y0 = blockIdx.y * 4, b = blockIdx.z;
  const ushort* hb = hP + (size_t)b * HWP * 32;

  for (int i = tid; i < 396 * 4; i += 512) {
    int oct = i & 3, rest = i >> 2;
    int xx = rest % 66, rr = rest / 66;
    *(uint4*)&xl[rest * 32 + oct * 8] =
        *(const uint4*)&hb[((size_t)(y0 + rr) * WP + (x0 + xx)) * 32 + oct * 8];
  }

  const int n = lane & 15, quad = lane >> 4;

  f4 acc[2][nM];
#pragma unroll
  for (int tu = 0; tu < 2; ++tu)
#pragma unroll
    for (int mt = 0; mt < nM; ++mt) acc[tu][mt] = f4{0.f, 0.f, 0.f, 0.f};

  bfrag whi[2][nM], wlo[2][nM];
#pragma unroll
  for (int mt = 0; mt < nM; ++mt) {
    whi[0][mt] = *(const bfrag*)&wp[(mt * 16 + n) * 32 + quad * 8];
    wlo[0][mt] = *(const bfrag*)&wp[((9 * NM16) + mt * 16 + n) * 32 + quad * 8];
  }
  __syncthreads();

#pragma unroll
  for (int tap = 0; tap < 9; ++tap) {
    const int dy = tap / 3, dx = tap % 3;
    const int cur = tap & 1, nxt = cur ^ 1;
    if (tap < 8) {   // prefetch next tap's weights under this tap's MFMAs
#pragma unroll
      for (int mt = 0; mt < nM; ++mt) {
        whi[nxt][mt] = *(const bfrag*)&wp[(((tap + 1) * NM16) + mt * 16 + n) * 32 + quad * 8];
        wlo[nxt][mt] = *(const bfrag*)&wp[(((9 + tap + 1) * NM16) + mt * 16 + n) * 32 + quad * 8];
      }
    }
#pragma unroll
    for (int tu = 0; tu < 2; ++tu) {
      int t = wid + tu * 8;
      int r = t >> 2, g = t & 3;
      int pix = (r + dy) * 66 + g * 16 + n + dx;
      bfrag bv = *(const bfrag*)&xl[pix * 32 + quad * 8];
#pragma unroll
      for (int mt = 0; mt < nM; ++mt) {
        acc[tu][mt] = __builtin_amdgcn_mfma_f32_16x16x32_bf16(whi[cur][mt], bv, acc[tu][mt], 0, 0, 0);
        acc[tu][mt] = __builtin_amdgcn_mfma_f32_16x16x32_bf16(wlo[cur][mt], bv, acc[tu][mt], 0, 0, 0);
      }
    }
  }

#pragma unroll
  for (int tu = 0; tu < 2; ++tu) {
    int t = wid + tu * 8;
    int r = t >> 2, g = t & 3;
    int gx = x0 + g * 16 + n, gy = y0 + r;
    size_t gpix = (size_t)gy * W_ + gx;

    float vs[nM][4];
    float pa = 0.f;
#pragma unroll
    for (int mt = 0; mt < nM; ++mt)
#pragma unroll
      for (int rg = 0; rg < 4; ++rg) {
        int co = mt * 16 + quad * 4 + rg;
        float v = (co < CO) ? acc[tu][mt][rg] * scale[co] + bias[co] : 0.f;
        vs[mt][rg] = v;
        pa += fabsf(v);
      }
    pa += __shfl_xor(pa, 16);
    pa += __shfl_xor(pa, 32);
    float inv = 1.f / (pa + EPS_);

    size_t base = ((size_t)b * HW + gpix) * (size_t)CO;
#pragma unroll
    for (int mt = 0; mt < nM; ++mt) {
      int cob = mt * 16 + quad * 4;
      if (cob < CO) {
        uint u0 = (uint)f2b(vs[mt][0] * inv) | ((uint)f2b(vs[mt][1] * inv) << 16);
        uint u1 = (uint)f2b(vs[mt][2] * inv) | ((uint)f2b(vs[mt][3] * inv) << 16);
        *(uint2*)&outw[base + cob] = uint2{u0, u1};
      }
    }
  }
}

// ---------------------------------------------------------------------------
// Plain bf16 conv1 (mask/conf/t), 512 threads.
// ---------------------------------------------------------------------------
template<int KB2, int MINW>
__global__ __launch_bounds__(512, MINW)
void conv1p(const float* __restrict__ xf, const float* __restrict__ hnsp,
            const ushort* __restrict__ wp, const ushort* __restrict__ wp2,
            const float* __restrict__ scale, const float* __restrict__ bias,
            ushort* __restrict__ outh)
{
  __shared__ ushort xl[396 * 32];
  __shared__ ushort xl2[KB2 ? 396 * 8 : 8];

  const int tid = threadIdx.x;
  const int lane = tid & 63;
  const int wid = tid >> 6;      // 0..7
  const int x0 = blockIdx.x * 64, y0 = blockIdx.y * 4, b = blockIdx.z;

  if (KB2) {
    for (int i = tid; i < 396; i += 512) {
      int xx = i % 66, rr = i / 66;
      int yy = y0 - 1 + rr, x = x0 - 1 + xx;
      float v0 = 0.f, v1 = 0.f, v2 = 0.f;
      if ((unsigned)yy < (unsigned)H_ && (unsigned)x < (unsigned)W_) {
        size_t pix = (size_t)yy * W_ + x;
        v0 = hnsp[((size_t)b * 3 + 0) * HW + pix];
        v1 = hnsp[((size_t)b * 3 + 1) * HW + pix];
        v2 = hnsp[((size_t)b * 3 + 2) * HW + pix];
      }
      ushort h0b = f2b(v0), h1b = f2b(v1), h2b = f2b(v2);
      ushort l0 = f2b(v0 - b2f(h0b)), l1 = f2b(v1 - b2f(h1b)), l2 = f2b(v2 - b2f(h2b));
      uint u0 = (uint)h0b | ((uint)h1b << 16);
      uint u1 = (uint)h2b | ((uint)l0 << 16);
      uint u2 = (uint)l1 | ((uint)l2 << 16);
      *(uint4*)&xl2[i * 8] = uint4{u0, u1, u2, 0};
    }
  }
  for (int i = tid; i < 396 * 4; i += 512) {
    int oct = i & 3, rest = i >> 2;
    int xx = rest % 66, rr = rest / 66;
    int yy = y0 - 1 + rr, x = x0 - 1 + xx;
    uint4 v = {0, 0, 0, 0};
    if ((unsigned)yy < (unsigned)H_ && (unsigned)x < (unsigned)W_) {
      const float* src = xf + ((size_t)b * 32 + oct * 8) * HW + (size_t)yy * W_ + x;
      uint u[4];
#pragma unroll
      for (int j = 0; j < 4; ++j) {
        float a = src[(size_t)(2 * j + 0) * HW];
        float c = src[(size_t)(2 * j + 1) * HW];
        u[j] = (uint)f2b(a) | ((uint)f2b(c) << 16);
      }
      v = uint4{u[0], u[1], u[2], u[3]};
    }
    *(uint4*)&xl[rest * 32 + oct * 8] = v;
  }
  __syncthreads();

  const int n = lane & 15, quad = lane >> 4;

  f4 acc[2][2];
#pragma unroll
  for (int tu = 0; tu < 2; ++tu)
#pragma unroll
    for (int mt = 0; mt < 2; ++mt) acc[tu][mt] = f4{0.f, 0.f, 0.f, 0.f};

#pragma unroll
  for (int tap = 0; tap < 9; ++tap) {
    int dy = tap / 3, dx = tap % 3;
    bfrag av[2];
#pragma unroll
    for (int mt = 0; mt < 2; ++mt)
      av[mt] = *(const bfrag*)&wp[((tap * 32) + mt * 16 + n) * 32 + quad * 8];
    bfrag a2[KB2 ? 2 : 1];
    if (KB2) {
#pragma unroll
      for (int mt = 0; mt < 2; ++mt) {
        BU t; t.u = uint4{0, 0, 0, 0};
        if (lane < 16) t.f = *(const bfrag*)&wp2[(tap * 32 + mt * 16 + lane) * 8];
        a2[mt] = t.f;
      }
    }
#pragma unroll
    for (int tu = 0; tu < 2; ++tu) {
      int t = wid + tu * 8;
      int r = t >> 2, g = t & 3;
      int pix = (r + dy) * 66 + g * 16 + n + dx;
      bfrag bv = *(const bfrag*)&xl[pix * 32 + quad * 8];
#pragma unroll
      for (int mt = 0; mt < 2; ++mt)
        acc[tu][mt] = __builtin_amdgcn_mfma_f32_16x16x32_bf16(av[mt], bv, acc[tu][mt], 0, 0, 0);
      if (KB2) {
        BU t2; t2.u = uint4{0, 0, 0, 0};
        if (lane < 16) t2.f = *(const bfrag*)&xl2[pix * 8];
#pragma unroll
        for (int mt = 0; mt < 2; ++mt)
          acc[tu][mt] = __builtin_amdgcn_mfma_f32_16x16x32_bf16(a2[mt], t2.f, acc[tu][mt], 0, 0, 0);
      }
    }
  }

#pragma unroll
  for (int tu = 0; tu < 2; ++tu) {
    int t = wid + tu * 8;
    int r = t >> 2, g = t & 3;
    int gx = x0 + g * 16 + n, gy = y0 + r;
    size_t bpix = (size_t)b * HWP + (size_t)(gy + 1) * WP + (gx + 1);
#pragma unroll
    for (int mt = 0; mt < 2; ++mt) {
      int cob = mt * 16 + quad * 4;
      float v0 = fmaxf(acc[tu][mt][0] * scale[cob + 0] + bias[cob + 0], 0.f);
      float v1 = fmaxf(acc[tu][mt][1] * scale[cob + 1] + bias[cob + 1], 0.f);
      float v2 = fmaxf(acc[tu][mt][2] * scale[cob + 2] + bias[cob + 2], 0.f);
      float v3 = fmaxf(acc[tu][mt][3] * scale[cob + 3] + bias[cob + 3], 0.f);
      uint u0 = (uint)f2b(v0) | ((uint)f2b(v1) << 16);
      uint u1 = (uint)f2b(v2) | ((uint)f2b(v3) << 16);
      *(uint2*)&outh[bpix * 32 + cob] = uint2{u0, u1};
    }
  }
}

// ---------------------------------------------------------------------------
// Small conv2 (CO=3), 512 threads. LDS-staged B tile; 9 weight frags resident.
// ---------------------------------------------------------------------------
template<int EPI>
__global__ __launch_bounds__(512, 4)
void conv2g(const ushort* __restrict__ hP, const ushort* __restrict__ wp,
            const float* __restrict__ bias, const float* __restrict__ h0,
            const float* __restrict__ hnsp, float* __restrict__ outf)
{
  __shared__ ushort xl[12672];

  const int tid = threadIdx.x;
  const int lane = tid & 63;
  const int wid = tid >> 6;      // 0..7
  const int x0 = blockIdx.x * 64, y0 = blockIdx.y * 4, b = blockIdx.z;
  const int n = lane & 15, quad = lane >> 4;
  const ushort* hb = hP + (size_t)b * HWP * 32;

  for (int i = tid; i < 396 * 4; i += 512) {
    int oct = i & 3, rest = i >> 2;
    int xx = rest % 66, rr = rest / 66;
    *(uint4*)&xl[rest * 32 + oct * 8] =
        *(const uint4*)&hb[((size_t)(y0 + rr) * WP + (x0 + xx)) * 32 + oct * 8];
  }

  bfrag av[9];
#pragma unroll
  for (int tap = 0; tap < 9; ++tap)
    av[tap] = *(const bfrag*)&wp[((tap * 16) + n) * 32 + quad * 8];

  f4 acc[2];
#pragma unroll
  for (int tu = 0; tu < 2; ++tu) acc[tu] = f4{0.f, 0.f, 0.f, 0.f};
  __syncthreads();

#pragma unroll
  for (int tap = 0; tap < 9; ++tap) {
    int dy = tap / 3, dx = tap % 3;
#pragma unroll
    for (int tu = 0; tu < 2; ++tu) {
      int t = wid + tu * 8;
      int r = t >> 2, g = t & 3;
      int pix = (r + dy) * 66 + g * 16 + n + dx;
      bfrag bv = *(const bfrag*)&xl[pix * 32 + quad * 8];
      acc[tu] = __builtin_amdgcn_mfma_f32_16x16x32_bf16(av[tap], bv, acc[tu], 0, 0, 0);
    }
  }

#pragma unroll
  for (int tu = 0; tu < 2; ++tu) {
    int t = wid + tu * 8;
    int r = t >> 2, g = t & 3;
    int gx = x0 + g * 16 + n, gy = y0 + r;
    size_t gpix = (size_t)gy * W_ + gx;
    size_t bpix = (size_t)b * HW + gpix;

    if constexpr (EPI == 2) {
      if (lane < 16) {
        float valid = (h0[bpix] > 0.001f) ? 1.f : 0.f;
#pragma unroll
        for (int rg = 0; rg < 3; ++rg) {
          float v = acc[tu][rg] + bias[rg];
          float sg = 1.f / (1.f + expf(-v));
          outf[((size_t)b * 3 + rg) * HW + gpix] = sg * valid;
        }
      }
    } else if constexpr (EPI == 3) {
      if (lane < 16) {
        float v0 = acc[tu][0] + bias[0];
        float v1 = acc[tu][1] + bias[1];
        float v2 = acc[tu][2] + bias[2];
        float m = fmaxf(v0, fmaxf(v1, v2));
        float e0 = expf(v0 - m), e1 = expf(v1 - m), e2 = expf(v2 - m);
        float inv = 1.f / (e0 + e1 + e2);
        outf[((size_t)b * 3 + 0) * HW + gpix] = e0 * inv;
        outf[((size_t)b * 3 + 1) * HW + gpix] = e1 * inv;
        outf[((size_t)b * 3 + 2) * HW + gpix] = e2 * inv;
      }
    } else if constexpr (EPI == 4) {
      if (lane < 16) {
        float v0 = acc[tu][0] + bias[0];
        float v1 = acc[tu][1] + bias[1];
        float v2 = acc[tu][2] + bias[2];
        float m = fmaxf(v0, fmaxf(v1, v2));
        float e0 = expf(v0 - m), e1 = expf(v1 - m), e2 = expf(v2 - m);
        float inv = 1.f / (e0 + e1 + e2);
        float a0 = hnsp[((size_t)b * 3 + 0) * HW + gpix];
        float a1 = hnsp[((size_t)b * 3 + 1) * HW + gpix];
        float a2v = hnsp[((size_t)b * 3 + 2) * HW + gpix];
        outf[bpix] = (e0 * a0 + e1 * a1 + e2 * a2v) * inv;
      }
    }
  }
}

// ---------------------------------------------------------------------------
__global__ __launch_bounds__(256)
void init_k(const float* __restrict__ hn, float* __restrict__ h3,
            float* __restrict__ h5, float* __restrict__ h7,
            float* __restrict__ hns)
{
  int t = blockIdx.x * 256 + threadIdx.x;
  if (t >= NP) return;
  float v = hn[t];
  h3[t] = v; h5[t] = v; h7[t] = v;
  int b = t / HW, rem = t - b * HW;
  hns[(size_t)b * 3 * HW + rem] = v;
}

// ---------------------------------------------------------------------------
// Propagation step. w planes pixel-major packed [B][HW][P] bf16 (uint4 reads).
// ---------------------------------------------------------------------------
__global__ __launch_bounds__(256)
void iterate_k(const float* __restrict__ h3i, const float* __restrict__ h5i,
               const float* __restrict__ h7i,
               float* __restrict__ h3o, float* __restrict__ h5o,
               float* __restrict__ h7o,
               const ushort* __restrict__ w3, const ushort* __restrict__ w5,
               const ushort* __restrict__ w7,
               const float* __restrict__ mask, const float* __restrict__ h0,
               float* __restrict__ hns, int chn, const float* __restrict__ conf)
{
  int t = blockIdx.x * 256 + threadIdx.x;
  if (t >= NP) return;
  int b = t / HW;
  int rem = t - b * HW;
  int y = rem / W_;
  int x = rem - y * W_;
  size_t pb = (size_t)b * HW;

  float h0v = h0[t];

  U8 a3; a3.u = *(const uint4*)&w3[((size_t)b * HW + rem) * 8];
  float s3 = 0.f, ws3 = 0.f;
#pragma unroll
  for (int p = 0; p < 8; ++p) {
    int tap = (p < 4) ? p : p + 1;
    int dy = tap / 3 - 1, dx = tap % 3 - 1;
    int yy = y + dy, xx = x + dx;
    float hv = ((unsigned)yy < (unsigned)H_ && (unsigned)xx < (unsigned)W_)
                   ? h3i[pb + yy * W_ + xx] : 0.f;
    float wv = b2f(a3.s[p]);
    ws3 += wv;
    s3 += wv * hv;
  }
  s3 += (1.f - ws3) * h3i[t];
  float m3 = mask[(size_t)(b * 3 + 0) * HW + rem];
  float n3 = (1.f - m3) * s3 + m3 * h0v;
  h3o[t] = n3;

  U8 a5[3];
  {
    const ushort* w5r = w5 + ((size_t)b * HW + rem) * 24;
#pragma unroll
    for (int q = 0; q < 3; ++q) a5[q].u = *(const uint4*)(w5r + q * 8);
  }
  float s5 = 0.f, ws5 = 0.f;
#pragma unroll
  for (int p = 0; p < 24; ++p) {
    int tap = (p < 12) ? p : p + 1;
    int dy = tap / 5 - 2, dx = tap % 5 - 2;
    int yy = y + dy, xx = x + dx;
    float hv = ((unsigned)yy < (unsigned)H_ && (unsigned)xx < (unsigned)W_)
                   ? h5i[pb + yy * W_ + xx] : 0.f;
    float wv = b2f(a5[p >> 3].s[p & 7]);
    ws5 += wv;
    s5 += wv * hv;
  }
  s5 += (1.f - ws5) * h5i[t];
  float m5 = mask[(size_t)(b * 3 + 1) * HW + rem];
  float n5 = (1.f - m5) * s5 + m5 * h0v;
  h5o[t] = n5;

  U8 a7[6];
  {
    const ushort* w7r = w7 + ((size_t)b * HW + rem) * 48;
#pragma unroll
    for (int q = 0; q < 6; ++q) a7[q].u = *(const uint4*)(w7r + q * 8);
  }
  float s7 = 0.f, ws7 = 0.f;
#pragma unroll
  for (int p = 0; p < 48; ++p) {
    int tap = (p < 24) ? p : p + 1;
    int dy = tap / 7 - 3, dx = tap % 7 - 3;
    int yy = y + dy, xx = x + dx;
    float hv = ((unsigned)yy < (unsigned)H_ && (unsigned)xx < (unsigned)W_)
                   ? h7i[pb + yy * W_ + xx] : 0.f;
    float wv = b2f(a7[p >> 3].s[p & 7]);
    ws7 += wv;
    s7 += wv * hv;
  }
  s7 += (1.f - ws7) * h7i[t];
  float m7 = mask[(size_t)(b * 3 + 2) * HW + rem];
  float n7 = (1.f - m7) * s7 + m7 * h0v;
  h7o[t] = n7;

  if (chn >= 0) {
    float c3 = conf[(size_t)(b * 3 + 0) * HW + rem];
    float c5 = conf[(size_t)(b * 3 + 1) * HW + rem];
    float c7 = conf[(size_t)(b * 3 + 2) * HW + rem];
    hns[(size_t)(b * 3 + chn) * HW + rem] = c3 * n3 + c5 * n5 + c7 * n7;
  }
}

extern "C" void kernel_launch(void* const* d_in, const int* in_sizes, int n_in,
                              void* d_out, int out_size, void* d_ws, size_t ws_size,
                              hipStream_t stream) {
  const float* fout = (const float*)d_in[0];
  const float* hn   = (const float*)d_in[1];
  const float* h0   = (const float*)d_in[2];
  const float* k3w1 = (const float*)d_in[3];
  const float* k3s1 = (const float*)d_in[4];
  const float* k3b1 = (const float*)d_in[5];
  const float* k3w2 = (const float*)d_in[6];
  const float* k3s2 = (const float*)d_in[7];
  const float* k3b2 = (const float*)d_in[8];
  const float* k5w1 = (const float*)d_in[9];
  const float* k5s1 = (const float*)d_in[10];
  const float* k5b1 = (const float*)d_in[11];
  const float* k5w2 = (const float*)d_in[12];
  const float* k5s2 = (const float*)d_in[13];
  const float* k5b2 = (const float*)d_in[14];
  const float* k7w1 = (const float*)d_in[15];
  const float* k7s1 = (const float*)d_in[16];
  const float* k7b1 = (const float*)d_in[17];
  const float* k7w2 = (const float*)d_in[18];
  const float* k7s2 = (const float*)d_in[19];
  const float* k7b2 = (const float*)d_in[20];
  const float* mw1  = (const float*)d_in[21];
  const float* ms1  = (const float*)d_in[22];
  const float* mb1  = (const float*)d_in[23];
  const float* mw2  = (const float*)d_in[24];
  const float* mbias2 = (const float*)d_in[25];
  const float* cw1  = (const float*)d_in[26];
  const float* cs1  = (const float*)d_in[27];
  const float* cb1  = (const float*)d_in[28];
  const float* cw2  = (const float*)d_in[29];
  const float* cbias2 = (const float*)d_in[30];
  const float* tw1  = (const float*)d_in[31];
  const float* ts1  = (const float*)d_in[32];
  const float* tb1  = (const float*)d_in[33];
  const float* tw2  = (const float*)d_in[34];
  const float* tbias2 = (const float*)d_in[35];

  float* out = (float*)d_out;

  // workspace: hP padded bf16 + w planes bf16 + fp32 mask/conf/hA/hns + wprep
  size_t hP_elems = (size_t)2 * HWP * 32;
  size_t need = hP_elems * 2 + (size_t)NP * (80 * 2 + 15 * 4) + (size_t)PREP_N * 2;
  if (ws_size < need) return;
  ushort* hPb  = (ushort*)d_ws;            // padded h, NHWC bf16
  ushort* w3   = hPb  + hP_elems;          // 8*NP  bf16 packed [B][HW][8]
  ushort* w5   = w3   + (size_t)8 * NP;    // 24*NP packed [B][HW][24]
  ushort* w7   = w5   + (size_t)24 * NP;   // 48*NP packed [B][HW][48]
  float* mask  = (float*)(w7 + (size_t)48 * NP);  // 3*NP f32
  float* conf  = mask + (size_t)3 * NP;    // 3*NP f32
  float* hA    = conf + (size_t)3 * NP;    // 6*NP f32 ping-pong
  float* hns   = hA   + (size_t)6 * NP;    // 3*NP f32
  ushort* wp   = (ushort*)(hns + (size_t)3 * NP); // PREP_N prepped weights

  dim3 blk(256);
  dim3 blkc(512);
  dim3 gc(W_ / 64, H_ / 4, B_);   // 19 x 64 x 2
  int ge = NP / 256;
  constexpr int PB = 2 * WP * 4 + 2 * (HP - 2) * 4;
  int gz = (2 * PB + 255) / 256;
  int gp = (PREP_N + 255) / 256;

  prep_k<<<gp, blk, 0, stream>>>(k3w1, k5w1, k7w1, k3w2, k5w2, k7w2,
                                 mw1, cw1, tw1, mw2, cw2, tw2, wp);
  zring_k<<<gz, blk, 0, stream>>>(hPb);

  // kernel-generator branches: split-precision conv1 + conv2
  convs1<<<gc, blkc, 0, stream>>>(fout, wp + PW1_K3, k3s1, k3b1, hPb);
  convs2<1, 4><<<gc, blkc, 0, stream>>>(hPb, wp + PW2_K3, k3s2, k3b2, w3, 8);
  convs1<<<gc, blkc, 0, stream>>>(fout, wp + PW1_K5, k5s1, k5b1, hPb);
  convs2<2, 4><<<gc, blkc, 0, stream>>>(hPb, wp + PW2_K5, k5s2, k5b2, w5, 24);
  convs1<<<gc, blkc, 0, stream>>>(fout, wp + PW1_K7, k7s1, k7b1, hPb);
  convs2<3, 3><<<gc, blkc, 0, stream>>>(hPb, wp + PW2_K7, k7s2, k7b2, w7, 48);

  // mask branch
  conv1p<0, 4><<<gc, blkc, 0, stream>>>(fout, nullptr, wp + PP1_M, nullptr, ms1, mb1, hPb);
  conv2g<2><<<gc, blkc, 0, stream>>>(hPb, wp + PG2_M, mbias2, h0, nullptr, mask);

  // confidence branch
  conv1p<0, 4><<<gc, blkc, 0, stream>>>(fout, nullptr, wp + PP1_C, nullptr, cs1, cb1, hPb);
  conv2g<3><<<gc, blkc, 0, stream>>>(hPb, wp + PG2_C, cbias2, nullptr, nullptr, conf);

  // propagation
  float* h3c = hA + (size_t)0 * NP; float* h3n = hA + (size_t)1 * NP;
  float* h5c = hA + (size_t)2 * NP; float* h5n = hA + (size_t)3 * NP;
  float* h7c = hA + (size_t)4 * NP; float* h7n = hA + (size_t)5 * NP;

  init_k<<<ge, blk, 0, stream>>>(hn, h3c, h5c, h7c, hns);
  for (int i = 0; i < 6; ++i) {
    int chn = (i == 2) ? 1 : ((i == 5) ? 2 : -1);
    iterate_k<<<ge, blk, 0, stream>>>(h3c, h5c, h7c, h3n, h5n, h7n,
                                      w3, w5, w7, mask, h0, hns, chn, conf);
    float* t;
    t = h3c; h3c = h3n; h3n = t;
    t = h5c; h5c = h5n; h5n = t;
    t = h7c; h7c = h7n; h7n = t;
  }

  // final temporal-weight branch
  conv1p<1, 3><<<gc, blkc, 0, stream>>>(fout, hns, wp + PP1_T, wp + PP1T2, ts1, tb1, hPb);
  conv2g<4><<<gc, blkc, 0, stream>>>(hPb, wp + PG2_T, tbias2, nullptr, hns, out);
}

// Round 19
// 899.228 us; speedup vs baseline: 1.1080x; 1.1080x over previous
//
#include <hip/hip_runtime.h>
#include <hip/hip_bf16.h>

constexpr int B_ = 2, H_ = 256, W_ = 1216;
constexpr int HW = H_ * W_;          // 311296
constexpr int NP = B_ * HW;          // 622592
constexpr int WP = W_ + 2;           // 1218 padded width
constexpr int HP = H_ + 2;           // 258  padded height
constexpr int HWP = HP * WP;         // 314244
constexpr float EPS_ = 1e-6f;

// prepped-weight region offsets (ushort units)
constexpr int PW1_K3 = 0;                    // [2][9][32][32] hi/lo
constexpr int PW1_K5 = 18432;
constexpr int PW1_K7 = 36864;
constexpr int PW2_K3 = 55296;                // [2][9][16][32]
constexpr int PW2_K5 = 64512;                // [2][9][32][32]
constexpr int PW2_K7 = 82944;                // [2][9][48][32]
constexpr int PP1_M  = 110592;               // [9][32][32] plain
constexpr int PP1_C  = 119808;
constexpr int PP1_T  = 129024;
constexpr int PP1T2  = 138240;               // [9][32][8]
constexpr int PG2_M  = 140544;               // [9][16][32] plain
constexpr int PG2_C  = 145152;
constexpr int PG2_T  = 149760;
constexpr int PREP_N = 154368;

typedef __bf16 bfrag __attribute__((ext_vector_type(8)));
typedef float f4 __attribute__((ext_vector_type(4)));

union BU { uint4 u; bfrag f; };
union U8 { uint4 u; ushort s[8]; };

__device__ __forceinline__ ushort f2b(float x) {
  uint u = __float_as_uint(x);
  u += 0x7fffu + ((u >> 16) & 1u);
  return (ushort)(u >> 16);
}
__device__ __forceinline__ float b2f(ushort u) {
  return __uint_as_float(((uint)u) << 16);
}

// ---------------------------------------------------------------------------
// One-shot weight prep: OIHW fp32 -> fragment-ready bf16 layouts (hi/lo
// precomputed, CO-padding zeroed).
// ---------------------------------------------------------------------------
__global__ __launch_bounds__(256)
void prep_k(const float* __restrict__ k3w1, const float* __restrict__ k5w1,
            const float* __restrict__ k7w1, const float* __restrict__ k3w2,
            const float* __restrict__ k5w2, const float* __restrict__ k7w2,
            const float* __restrict__ mw1, const float* __restrict__ cw1,
            const float* __restrict__ tw1, const float* __restrict__ mw2,
            const float* __restrict__ cw2, const float* __restrict__ tw2,
            ushort* __restrict__ wp)
{
  int i = blockIdx.x * 256 + threadIdx.x;
  if (i >= PREP_N) return;
  ushort outv;
  if (i < PW2_K3) {                       // conv1 chains hi/lo [c][2][9][32][32]
    int c = i / 18432, r = i % 18432;
    const float* src = (c == 0) ? k3w1 : (c == 1) ? k5w1 : k7w1;
    int ci = r & 31; int t1 = r >> 5;
    int co = t1 & 31; int t2 = t1 >> 5;
    int tap = t2 % 9, half = t2 / 9;
    float v = src[(co * 32 + ci) * 9 + tap];
    ushort hi = f2b(v);
    outv = half ? f2b(v - b2f(hi)) : hi;
  } else if (i < PP1_M) {                 // conv2 chains [2][9][NM16][32]
    int r = i - PW2_K3;
    const float* src; int NM16, CO;
    if (r < 9216)       { src = k3w2; NM16 = 16; CO = 8; }
    else if (r < 27648) { src = k5w2; NM16 = 32; CO = 24; r -= 9216; }
    else                { src = k7w2; NM16 = 48; CO = 48; r -= 27648; }
    int ci = r & 31; int t1 = r >> 5;
    int co = t1 % NM16; int t2 = t1 / NM16;
    int tap = t2 % 9, half = t2 / 9;
    if (co < CO) {
      float v = src[(co * 32 + ci) * 9 + tap];
      ushort hi = f2b(v);
      outv = half ? f2b(v - b2f(hi)) : hi;
    } else outv = 0;
  } else if (i < PP1T2) {                 // conv1p plain [c][9][32][32]
    int r = i - PP1_M;
    int c = r / 9216; r %= 9216;
    const float* src = (c == 0) ? mw1 : (c == 1) ? cw1 : tw1;
    int CIN = (c == 2) ? 35 : 32;
    int ci = r & 31; int t1 = r >> 5;
    int co = t1 & 31, tap = t1 >> 5;
    outv = f2b(src[(co * CIN + ci) * 9 + tap]);
  } else if (i < PG2_M) {                 // t-branch extra K [9][32][8]
    int r = i - PP1T2;
    int c8 = r & 7; int t1 = r >> 3;
    int co = t1 & 31, tap = t1 >> 5;
    int cc = (c8 < 3) ? c8 : ((c8 < 6) ? c8 - 3 : -1);
    outv = (cc >= 0) ? f2b(tw1[(co * 35 + 32 + cc) * 9 + tap]) : (ushort)0;
  } else {                                // conv2g [c][9][16][32]
    int r = i - PG2_M;
    int c = r / 4608; r %= 4608;
    const float* src = (c == 0) ? mw2 : (c == 1) ? cw2 : tw2;
    int ci = r & 31; int t1 = r >> 5;
    int co = t1 & 15, tap = t1 >> 4;
    outv = (co < 3) ? f2b(src[(co * 32 + ci) * 9 + tap]) : (ushort)0;
  }
  wp[i] = outv;
}

// ---------------------------------------------------------------------------
// Zero the pad ring of hP (padded NHWC bf16 [b][HP][WP][32]).
// ---------------------------------------------------------------------------
__global__ __launch_bounds__(256)
void zring_k(ushort* __restrict__ hP) {
  constexpr int PB = 2 * WP * 4 + 2 * (HP - 2) * 4;   // uint4 units per batch
  int i = blockIdx.x * 256 + threadIdx.x;
  if (i >= 2 * PB) return;
  int b = i / PB, r = i % PB;
  size_t idx;
  if (r < WP * 4) idx = (size_t)r;
  else if (r < 2 * WP * 4) idx = (size_t)(HP - 1) * WP * 4 + (r - WP * 4);
  else {
    int q = r - 2 * WP * 4;
    int row = q >> 3, k = q & 7;
    int col = (k < 4) ? k : (WP - 1) * 4 + (k - 4);
    idx = (size_t)(row + 1) * WP * 4 + col;
  }
  *(uint4*)&hP[(size_t)b * HWP * 32 + idx * 8] = uint4{0, 0, 0, 0};
}

// ---------------------------------------------------------------------------
// Split-precision conv1 (w-chains): fout(fp32 NCHW) -> hP(bf16 padded NHWC).
// ---------------------------------------------------------------------------
__global__ __launch_bounds__(256, 3)
void convs1(const float* __restrict__ xf, const ushort* __restrict__ wp,
            const float* __restrict__ scale, const float* __restrict__ bias,
            ushort* __restrict__ outh)
{
  __shared__ ushort xl[25344];   // hi [0,12672) | lo [12672,25344)

  const int tid = threadIdx.x;
  const int lane = tid & 63;
  const int wid = tid >> 6;
  const int x0 = blockIdx.x * 64, y0 = blockIdx.y * 4, b = blockIdx.z;

  for (int i = tid; i < 396 * 4; i += 256) {
    int oct = i & 3, rest = i >> 2;
    int xx = rest % 66, rr = rest / 66;
    int yy = y0 - 1 + rr, x = x0 - 1 + xx;
    uint4 vh = {0, 0, 0, 0}, vl = {0, 0, 0, 0};
    if ((unsigned)yy < (unsigned)H_ && (unsigned)x < (unsigned)W_) {
      const float* src = xf + ((size_t)b * 32 + oct * 8) * HW + (size_t)yy * W_ + x;
      uint uh[4], ul[4];
#pragma unroll
      for (int j = 0; j < 4; ++j) {
        float a = src[(size_t)(2 * j + 0) * HW];
        float c = src[(size_t)(2 * j + 1) * HW];
        ushort ah = f2b(a), ch = f2b(c);
        ushort al = f2b(a - b2f(ah)), cl = f2b(c - b2f(ch));
        uh[j] = (uint)ah | ((uint)ch << 16);
        ul[j] = (uint)al | ((uint)cl << 16);
      }
      vh = uint4{uh[0], uh[1], uh[2], uh[3]};
      vl = uint4{ul[0], ul[1], ul[2], ul[3]};
    }
    *(uint4*)&xl[rest * 32 + oct * 8] = vh;
    *(uint4*)&xl[12672 + rest * 32 + oct * 8] = vl;
  }
  __syncthreads();

  const int n = lane & 15, quad = lane >> 4;

  f4 acc[4][2];
#pragma unroll
  for (int tu = 0; tu < 4; ++tu)
#pragma unroll
    for (int mt = 0; mt < 2; ++mt) acc[tu][mt] = f4{0.f, 0.f, 0.f, 0.f};

#pragma unroll
  for (int tap = 0; tap < 9; ++tap) {
    int dy = tap / 3, dx = tap % 3;
    bfrag avhi[2], avlo[2];
#pragma unroll
    for (int mt = 0; mt < 2; ++mt) {
      avhi[mt] = *(const bfrag*)&wp[((tap * 32) + mt * 16 + n) * 32 + quad * 8];
      avlo[mt] = *(const bfrag*)&wp[(((9 + tap) * 32) + mt * 16 + n) * 32 + quad * 8];
    }
#pragma unroll
    for (int tu = 0; tu < 4; ++tu) {
      int t = wid + tu * 4;
      int r = t >> 2, g = t & 3;
      int pix = (r + dy) * 66 + g * 16 + n + dx;
      bfrag bhi = *(const bfrag*)&xl[pix * 32 + quad * 8];
      bfrag blo = *(const bfrag*)&xl[12672 + pix * 32 + quad * 8];
#pragma unroll
      for (int mt = 0; mt < 2; ++mt) {
        acc[tu][mt] = __builtin_amdgcn_mfma_f32_16x16x32_bf16(avhi[mt], bhi, acc[tu][mt], 0, 0, 0);
        acc[tu][mt] = __builtin_amdgcn_mfma_f32_16x16x32_bf16(avhi[mt], blo, acc[tu][mt], 0, 0, 0);
        acc[tu][mt] = __builtin_amdgcn_mfma_f32_16x16x32_bf16(avlo[mt], bhi, acc[tu][mt], 0, 0, 0);
      }
    }
  }

#pragma unroll
  for (int tu = 0; tu < 4; ++tu) {
    int t = wid + tu * 4;
    int r = t >> 2, g = t & 3;
    int gx = x0 + g * 16 + n, gy = y0 + r;
    size_t bpix = (size_t)b * HWP + (size_t)(gy + 1) * WP + (gx + 1);
#pragma unroll
    for (int mt = 0; mt < 2; ++mt) {
      int cob = mt * 16 + quad * 4;
      float v0 = fmaxf(acc[tu][mt][0] * scale[cob + 0] + bias[cob + 0], 0.f);
      float v1 = fmaxf(acc[tu][mt][1] * scale[cob + 1] + bias[cob + 1], 0.f);
      float v2 = fmaxf(acc[tu][mt][2] * scale[cob + 2] + bias[cob + 2], 0.f);
      float v3 = fmaxf(acc[tu][mt][3] * scale[cob + 3] + bias[cob + 3], 0.f);
      uint u0 = (uint)f2b(v0) | ((uint)f2b(v1) << 16);
      uint u1 = (uint)f2b(v2) | ((uint)f2b(v3) << 16);
      *(uint2*)&outh[bpix * 32 + cob] = uint2{u0, u1};
    }
  }
}

// ---------------------------------------------------------------------------
// Split-precision conv2 (w-chains). LDS-staged B tile (batches global
// latency into one barrier; ds_read feeds MFMA), double-buffered per-tap
// weight frags, pixel-major packed output [B][HW][CO].
// ---------------------------------------------------------------------------
template<int nM, int MINW>
__global__ __launch_bounds__(256, MINW)
void convs2(const ushort* __restrict__ hP, const ushort* __restrict__ wp,
            const float* __restrict__ scale, const float* __restrict__ bias,
            ushort* __restrict__ outw, int CO)
{
  __shared__ ushort xl[12672];   // 6 rows x 66 px x 32 ch bf16 = 25344 B

  constexpr int NM16 = nM * 16;
  const int tid = threadIdx.x;
  const int lane = tid & 63;
  const int wid = tid >> 6;
  const int x0 = blockIdx.x * 64, y0 = blockIdx.y * 4, b = blockIdx.z;
  const ushort* hb = hP + (size_t)b * HWP * 32;

  // stage padded-hP tile: rows y0..y0+5, cols x0..x0+65 (all in-range: pad ring)
  for (int i = tid; i < 396 * 4; i += 256) {
    int oct = i & 3, rest = i >> 2;
    int xx = rest % 66, rr = rest / 66;
    *(uint4*)&xl[rest * 32 + oct * 8] =
        *(const uint4*)&hb[((size_t)(y0 + rr) * WP + (x0 + xx)) * 32 + oct * 8];
  }

  const int n = lane & 15, quad = lane >> 4;

  f4 acc[4][nM];
#pragma unroll
  for (int tu = 0; tu < 4; ++tu)
#pragma unroll
    for (int mt = 0; mt < nM; ++mt) acc[tu][mt] = f4{0.f, 0.f, 0.f, 0.f};

  // preload tap-0 weights (independent of LDS)
  bfrag whi[2][nM], wlo[2][nM];
#pragma unroll
  for (int mt = 0; mt < nM; ++mt) {
    whi[0][mt] = *(const bfrag*)&wp[(mt * 16 + n) * 32 + quad * 8];
    wlo[0][mt] = *(const bfrag*)&wp[((9 * NM16) + mt * 16 + n) * 32 + quad * 8];
  }
  __syncthreads();

#pragma unroll
  for (int tap = 0; tap < 9; ++tap) {
    const int dy = tap / 3, dx = tap % 3;
    const int cur = tap & 1, nxt = cur ^ 1;
    if (tap < 8) {   // prefetch next tap's weights under this tap's MFMAs
#pragma unroll
      for (int mt = 0; mt < nM; ++mt) {
        whi[nxt][mt] = *(const bfrag*)&wp[(((tap + 1) * NM16) + mt * 16 + n) * 32 + quad * 8];
        wlo[nxt][mt] = *(const bfrag*)&wp[(((9 + tap + 1) * NM16) + mt * 16 + n) * 32 + quad * 8];
      }
    }
#pragma unroll
    for (int tu = 0; tu < 4; ++tu) {
      int t = wid + tu * 4;
      int r = t >> 2, g = t & 3;
      int pix = (r + dy) * 66 + g * 16 + n + dx;
      bfrag bv = *(const bfrag*)&xl[pix * 32 + quad * 8];
#pragma unroll
      for (int mt = 0; mt < nM; ++mt) {
        acc[tu][mt] = __builtin_amdgcn_mfma_f32_16x16x32_bf16(whi[cur][mt], bv, acc[tu][mt], 0, 0, 0);
        acc[tu][mt] = __builtin_amdgcn_mfma_f32_16x16x32_bf16(wlo[cur][mt], bv, acc[tu][mt], 0, 0, 0);
      }
    }
  }

#pragma unroll
  for (int tu = 0; tu < 4; ++tu) {
    int t = wid + tu * 4;
    int r = t >> 2, g = t & 3;
    int gx = x0 + g * 16 + n, gy = y0 + r;
    size_t gpix = (size_t)gy * W_ + gx;

    float vs[nM][4];
    float pa = 0.f;
#pragma unroll
    for (int mt = 0; mt < nM; ++mt)
#pragma unroll
      for (int rg = 0; rg < 4; ++rg) {
        int co = mt * 16 + quad * 4 + rg;
        float v = (co < CO) ? acc[tu][mt][rg] * scale[co] + bias[co] : 0.f;
        vs[mt][rg] = v;
        pa += fabsf(v);
      }
    pa += __shfl_xor(pa, 16);
    pa += __shfl_xor(pa, 32);
    float inv = 1.f / (pa + EPS_);

    // packed pixel-major store [B][HW][CO], 8B per mt-group
    size_t base = ((size_t)b * HW + gpix) * (size_t)CO;
#pragma unroll
    for (int mt = 0; mt < nM; ++mt) {
      int cob = mt * 16 + quad * 4;
      if (cob < CO) {
        uint u0 = (uint)f2b(vs[mt][0] * inv) | ((uint)f2b(vs[mt][1] * inv) << 16);
        uint u1 = (uint)f2b(vs[mt][2] * inv) | ((uint)f2b(vs[mt][3] * inv) << 16);
        *(uint2*)&outw[base + cob] = uint2{u0, u1};
      }
    }
  }
}

// ---------------------------------------------------------------------------
// Plain bf16 conv1 (mask/conf/t): fout(fp32 NCHW) -> hP (padded).
// ---------------------------------------------------------------------------
template<int KB2, int MINW>
__global__ __launch_bounds__(256, MINW)
void conv1p(const float* __restrict__ xf, const float* __restrict__ hnsp,
            const ushort* __restrict__ wp, const ushort* __restrict__ wp2,
            const float* __restrict__ scale, const float* __restrict__ bias,
            ushort* __restrict__ outh)
{
  __shared__ ushort xl[396 * 32];
  __shared__ ushort xl2[KB2 ? 396 * 8 : 8];

  const int tid = threadIdx.x;
  const int lane = tid & 63;
  const int wid = tid >> 6;
  const int x0 = blockIdx.x * 64, y0 = blockIdx.y * 4, b = blockIdx.z;

  if (KB2) {
    for (int i = tid; i < 396; i += 256) {
      int xx = i % 66, rr = i / 66;
      int yy = y0 - 1 + rr, x = x0 - 1 + xx;
      float v0 = 0.f, v1 = 0.f, v2 = 0.f;
      if ((unsigned)yy < (unsigned)H_ && (unsigned)x < (unsigned)W_) {
        size_t pix = (size_t)yy * W_ + x;
        v0 = hnsp[((size_t)b * 3 + 0) * HW + pix];
        v1 = hnsp[((size_t)b * 3 + 1) * HW + pix];
        v2 = hnsp[((size_t)b * 3 + 2) * HW + pix];
      }
      ushort h0b = f2b(v0), h1b = f2b(v1), h2b = f2b(v2);
      ushort l0 = f2b(v0 - b2f(h0b)), l1 = f2b(v1 - b2f(h1b)), l2 = f2b(v2 - b2f(h2b));
      uint u0 = (uint)h0b | ((uint)h1b << 16);
      uint u1 = (uint)h2b | ((uint)l0 << 16);
      uint u2 = (uint)l1 | ((uint)l2 << 16);
      *(uint4*)&xl2[i * 8] = uint4{u0, u1, u2, 0};
    }
  }
  for (int i = tid; i < 396 * 4; i += 256) {
    int oct = i & 3, rest = i >> 2;
    int xx = rest % 66, rr = rest / 66;
    int yy = y0 - 1 + rr, x = x0 - 1 + xx;
    uint4 v = {0, 0, 0, 0};
    if ((unsigned)yy < (unsigned)H_ && (unsigned)x < (unsigned)W_) {
      const float* src = xf + ((size_t)b * 32 + oct * 8) * HW + (size_t)yy * W_ + x;
      uint u[4];
#pragma unroll
      for (int j = 0; j < 4; ++j) {
        float a = src[(size_t)(2 * j + 0) * HW];
        float c = src[(size_t)(2 * j + 1) * HW];
        u[j] = (uint)f2b(a) | ((uint)f2b(c) << 16);
      }
      v = uint4{u[0], u[1], u[2], u[3]};
    }
    *(uint4*)&xl[rest * 32 + oct * 8] = v;
  }
  __syncthreads();

  const int n = lane & 15, quad = lane >> 4;

  f4 acc[4][2];
#pragma unroll
  for (int tu = 0; tu < 4; ++tu)
#pragma unroll
    for (int mt = 0; mt < 2; ++mt) acc[tu][mt] = f4{0.f, 0.f, 0.f, 0.f};

#pragma unroll
  for (int tap = 0; tap < 9; ++tap) {
    int dy = tap / 3, dx = tap % 3;
    bfrag av[2];
#pragma unroll
    for (int mt = 0; mt < 2; ++mt)
      av[mt] = *(const bfrag*)&wp[((tap * 32) + mt * 16 + n) * 32 + quad * 8];
    bfrag a2[KB2 ? 2 : 1];
    if (KB2) {
#pragma unroll
      for (int mt = 0; mt < 2; ++mt) {
        BU t; t.u = uint4{0, 0, 0, 0};
        if (lane < 16) t.f = *(const bfrag*)&wp2[(tap * 32 + mt * 16 + lane) * 8];
        a2[mt] = t.f;
      }
    }
#pragma unroll
    for (int tu = 0; tu < 4; ++tu) {
      int t = wid + tu * 4;
      int r = t >> 2, g = t & 3;
      int pix = (r + dy) * 66 + g * 16 + n + dx;
      bfrag bv = *(const bfrag*)&xl[pix * 32 + quad * 8];
#pragma unroll
      for (int mt = 0; mt < 2; ++mt)
        acc[tu][mt] = __builtin_amdgcn_mfma_f32_16x16x32_bf16(av[mt], bv, acc[tu][mt], 0, 0, 0);
      if (KB2) {
        BU t2; t2.u = uint4{0, 0, 0, 0};
        if (lane < 16) t2.f = *(const bfrag*)&xl2[pix * 8];
#pragma unroll
        for (int mt = 0; mt < 2; ++mt)
          acc[tu][mt] = __builtin_amdgcn_mfma_f32_16x16x32_bf16(a2[mt], t2.f, acc[tu][mt], 0, 0, 0);
      }
    }
  }

#pragma unroll
  for (int tu = 0; tu < 4; ++tu) {
    int t = wid + tu * 4;
    int r = t >> 2, g = t & 3;
    int gx = x0 + g * 16 + n, gy = y0 + r;
    size_t bpix = (size_t)b * HWP + (size_t)(gy + 1) * WP + (gx + 1);
#pragma unroll
    for (int mt = 0; mt < 2; ++mt) {
      int cob = mt * 16 + quad * 4;
      float v0 = fmaxf(acc[tu][mt][0] * scale[cob + 0] + bias[cob + 0], 0.f);
      float v1 = fmaxf(acc[tu][mt][1] * scale[cob + 1] + bias[cob + 1], 0.f);
      float v2 = fmaxf(acc[tu][mt][2] * scale[cob + 2] + bias[cob + 2], 0.f);
      float v3 = fmaxf(acc[tu][mt][3] * scale[cob + 3] + bias[cob + 3], 0.f);
      uint u0 = (uint)f2b(v0) | ((uint)f2b(v1) << 16);
      uint u1 = (uint)f2b(v2) | ((uint)f2b(v3) << 16);
      *(uint2*)&outh[bpix * 32 + cob] = uint2{u0, u1};
    }
  }
}

// ---------------------------------------------------------------------------
// Small conv2 (CO=3). LDS-staged B tile; 9 weight frags resident.
// ---------------------------------------------------------------------------
template<int EPI>
__global__ __launch_bounds__(256, 4)
void conv2g(const ushort* __restrict__ hP, const ushort* __restrict__ wp,
            const float* __restrict__ bias, const float* __restrict__ h0,
            const float* __restrict__ hnsp, float* __restrict__ outf)
{
  __shared__ ushort xl[12672];

  const int tid = threadIdx.x;
  const int lane = tid & 63;
  const int wid = tid >> 6;
  const int x0 = blockIdx.x * 64, y0 = blockIdx.y * 4, b = blockIdx.z;
  const int n = lane & 15, quad = lane >> 4;
  const ushort* hb = hP + (size_t)b * HWP * 32;

  for (int i = tid; i < 396 * 4; i += 256) {
    int oct = i & 3, rest = i >> 2;
    int xx = rest % 66, rr = rest / 66;
    *(uint4*)&xl[rest * 32 + oct * 8] =
        *(const uint4*)&hb[((size_t)(y0 + rr) * WP + (x0 + xx)) * 32 + oct * 8];
  }

  bfrag av[9];
#pragma unroll
  for (int tap = 0; tap < 9; ++tap)
    av[tap] = *(const bfrag*)&wp[((tap * 16) + n) * 32 + quad * 8];

  f4 acc[4];
#pragma unroll
  for (int tu = 0; tu < 4; ++tu) acc[tu] = f4{0.f, 0.f, 0.f, 0.f};
  __syncthreads();

#pragma unroll
  for (int tap = 0; tap < 9; ++tap) {
    int dy = tap / 3, dx = tap % 3;
#pragma unroll
    for (int tu = 0; tu < 4; ++tu) {
      int t = wid + tu * 4;
      int r = t >> 2, g = t & 3;
      int pix = (r + dy) * 66 + g * 16 + n + dx;
      bfrag bv = *(const bfrag*)&xl[pix * 32 + quad * 8];
      acc[tu] = __builtin_amdgcn_mfma_f32_16x16x32_bf16(av[tap], bv, acc[tu], 0, 0, 0);
    }
  }

#pragma unroll
  for (int tu = 0; tu < 4; ++tu) {
    int t = wid + tu * 4;
    int r = t >> 2, g = t & 3;
    int gx = x0 + g * 16 + n, gy = y0 + r;
    size_t gpix = (size_t)gy * W_ + gx;
    size_t bpix = (size_t)b * HW + gpix;

    if constexpr (EPI == 2) {
      if (lane < 16) {
        float valid = (h0[bpix] > 0.001f) ? 1.f : 0.f;
#pragma unroll
        for (int rg = 0; rg < 3; ++rg) {
          float v = acc[tu][rg] + bias[rg];
          float sg = 1.f / (1.f + expf(-v));
          outf[((size_t)b * 3 + rg) * HW + gpix] = sg * valid;
        }
      }
    } else if constexpr (EPI == 3) {
      if (lane < 16) {
        float v0 = acc[tu][0] + bias[0];
        float v1 = acc[tu][1] + bias[1];
        float v2 = acc[tu][2] + bias[2];
        float m = fmaxf(v0, fmaxf(v1, v2));
        float e0 = expf(v0 - m), e1 = expf(v1 - m), e2 = expf(v2 - m);
        float inv = 1.f / (e0 + e1 + e2);
        outf[((size_t)b * 3 + 0) * HW + gpix] = e0 * inv;
        outf[((size_t)b * 3 + 1) * HW + gpix] = e1 * inv;
        outf[((size_t)b * 3 + 2) * HW + gpix] = e2 * inv;
      }
    } else if constexpr (EPI == 4) {
      if (lane < 16) {
        float v0 = acc[tu][0] + bias[0];
        float v1 = acc[tu][1] + bias[1];
        float v2 = acc[tu][2] + bias[2];
        float m = fmaxf(v0, fmaxf(v1, v2));
        float e0 = expf(v0 - m), e1 = expf(v1 - m), e2 = expf(v2 - m);
        float inv = 1.f / (e0 + e1 + e2);
        float a0 = hnsp[((size_t)b * 3 + 0) * HW + gpix];
        float a1 = hnsp[((size_t)b * 3 + 1) * HW + gpix];
        float a2v = hnsp[((size_t)b * 3 + 2) * HW + gpix];
        outf[bpix] = (e0 * a0 + e1 * a1 + e2 * a2v) * inv;
      }
    }
  }
}

// ---------------------------------------------------------------------------
__global__ __launch_bounds__(256)
void init_k(const float* __restrict__ hn, float* __restrict__ h3,
            float* __restrict__ h5, float* __restrict__ h7,
            float* __restrict__ hns)
{
  int t = blockIdx.x * 256 + threadIdx.x;
  if (t >= NP) return;
  float v = hn[t];
  h3[t] = v; h5[t] = v; h7[t] = v;
  int b = t / HW, rem = t - b * HW;
  hns[(size_t)b * 3 * HW + rem] = v;
}

// ---------------------------------------------------------------------------
// Propagation step. w planes pixel-major packed [B][HW][P] bf16 (uint4 reads).
// ---------------------------------------------------------------------------
__global__ __launch_bounds__(256)
void iterate_k(const float* __restrict__ h3i, const float* __restrict__ h5i,
               const float* __restrict__ h7i,
               float* __restrict__ h3o, float* __restrict__ h5o,
               float* __restrict__ h7o,
               const ushort* __restrict__ w3, const ushort* __restrict__ w5,
               const ushort* __restrict__ w7,
               const float* __restrict__ mask, const float* __restrict__ h0,
               float* __restrict__ hns, int chn, const float* __restrict__ conf)
{
  int t = blockIdx.x * 256 + threadIdx.x;
  if (t >= NP) return;
  int b = t / HW;
  int rem = t - b * HW;
  int y = rem / W_;
  int x = rem - y * W_;
  size_t pb = (size_t)b * HW;

  float h0v = h0[t];

  U8 a3; a3.u = *(const uint4*)&w3[((size_t)b * HW + rem) * 8];
  float s3 = 0.f, ws3 = 0.f;
#pragma unroll
  for (int p = 0; p < 8; ++p) {
    int tap = (p < 4) ? p : p + 1;
    int dy = tap / 3 - 1, dx = tap % 3 - 1;
    int yy = y + dy, xx = x + dx;
    float hv = ((unsigned)yy < (unsigned)H_ && (unsigned)xx < (unsigned)W_)
                   ? h3i[pb + yy * W_ + xx] : 0.f;
    float wv = b2f(a3.s[p]);
    ws3 += wv;
    s3 += wv * hv;
  }
  s3 += (1.f - ws3) * h3i[t];
  float m3 = mask[(size_t)(b * 3 + 0) * HW + rem];
  float n3 = (1.f - m3) * s3 + m3 * h0v;
  h3o[t] = n3;

  U8 a5[3];
  {
    const ushort* w5r = w5 + ((size_t)b * HW + rem) * 24;
#pragma unroll
    for (int q = 0; q < 3; ++q) a5[q].u = *(const uint4*)(w5r + q * 8);
  }
  float s5 = 0.f, ws5 = 0.f;
#pragma unroll
  for (int p = 0; p < 24; ++p) {
    int tap = (p < 12) ? p : p + 1;
    int dy = tap / 5 - 2, dx = tap % 5 - 2;
    int yy = y + dy, xx = x + dx;
    float hv = ((unsigned)yy < (unsigned)H_ && (unsigned)xx < (unsigned)W_)
                   ? h5i[pb + yy * W_ + xx] : 0.f;
    float wv = b2f(a5[p >> 3].s[p & 7]);
    ws5 += wv;
    s5 += wv * hv;
  }
  s5 += (1.f - ws5) * h5i[t];
  float m5 = mask[(size_t)(b * 3 + 1) * HW + rem];
  float n5 = (1.f - m5) * s5 + m5 * h0v;
  h5o[t] = n5;

  U8 a7[6];
  {
    const ushort* w7r = w7 + ((size_t)b * HW + rem) * 48;
#pragma unroll
    for (int q = 0; q < 6; ++q) a7[q].u = *(const uint4*)(w7r + q * 8);
  }
  float s7 = 0.f, ws7 = 0.f;
#pragma unroll
  for (int p = 0; p < 48; ++p) {
    int tap = (p < 24) ? p : p + 1;
    int dy = tap / 7 - 3, dx = tap % 7 - 3;
    int yy = y + dy, xx = x + dx;
    float hv = ((unsigned)yy < (unsigned)H_ && (unsigned)xx < (unsigned)W_)
                   ? h7i[pb + yy * W_ + xx] : 0.f;
    float wv = b2f(a7[p >> 3].s[p & 7]);
    ws7 += wv;
    s7 += wv * hv;
  }
  s7 += (1.f - ws7) * h7i[t];
  float m7 = mask[(size_t)(b * 3 + 2) * HW + rem];
  float n7 = (1.f - m7) * s7 + m7 * h0v;
  h7o[t] = n7;

  if (chn >= 0) {
    float c3 = conf[(size_t)(b * 3 + 0) * HW + rem];
    float c5 = conf[(size_t)(b * 3 + 1) * HW + rem];
    float c7 = conf[(size_t)(b * 3 + 2) * HW + rem];
    hns[(size_t)(b * 3 + chn) * HW + rem] = c3 * n3 + c5 * n5 + c7 * n7;
  }
}

extern "C" void kernel_launch(void* const* d_in, const int* in_sizes, int n_in,
                              void* d_out, int out_size, void* d_ws, size_t ws_size,
                              hipStream_t stream) {
  const float* fout = (const float*)d_in[0];
  const float* hn   = (const float*)d_in[1];
  const float* h0   = (const float*)d_in[2];
  const float* k3w1 = (const float*)d_in[3];
  const float* k3s1 = (const float*)d_in[4];
  const float* k3b1 = (const float*)d_in[5];
  const float* k3w2 = (const float*)d_in[6];
  const float* k3s2 = (const float*)d_in[7];
  const float* k3b2 = (const float*)d_in[8];
  const float* k5w1 = (const float*)d_in[9];
  const float* k5s1 = (const float*)d_in[10];
  const float* k5b1 = (const float*)d_in[11];
  const float* k5w2 = (const float*)d_in[12];
  const float* k5s2 = (const float*)d_in[13];
  const float* k5b2 = (const float*)d_in[14];
  const float* k7w1 = (const float*)d_in[15];
  const float* k7s1 = (const float*)d_in[16];
  const float* k7b1 = (const float*)d_in[17];
  const float* k7w2 = (const float*)d_in[18];
  const float* k7s2 = (const float*)d_in[19];
  const float* k7b2 = (const float*)d_in[20];
  const float* mw1  = (const float*)d_in[21];
  const float* ms1  = (const float*)d_in[22];
  const float* mb1  = (const float*)d_in[23];
  const float* mw2  = (const float*)d_in[24];
  const float* mbias2 = (const float*)d_in[25];
  const float* cw1  = (const float*)d_in[26];
  const float* cs1  = (const float*)d_in[27];
  const float* cb1  = (const float*)d_in[28];
  const float* cw2  = (const float*)d_in[29];
  const float* cbias2 = (const float*)d_in[30];
  const float* tw1  = (const float*)d_in[31];
  const float* ts1  = (const float*)d_in[32];
  const float* tb1  = (const float*)d_in[33];
  const float* tw2  = (const float*)d_in[34];
  const float* tbias2 = (const float*)d_in[35];

  float* out = (float*)d_out;

  // workspace: hP padded bf16 + w planes bf16 + fp32 mask/conf/hA/hns + wprep
  size_t hP_elems = (size_t)2 * HWP * 32;
  size_t need = hP_elems * 2 + (size_t)NP * (80 * 2 + 15 * 4) + (size_t)PREP_N * 2;
  if (ws_size < need) return;
  ushort* hPb  = (ushort*)d_ws;            // padded h, NHWC bf16
  ushort* w3   = hPb  + hP_elems;          // 8*NP  bf16 packed [B][HW][8]
  ushort* w5   = w3   + (size_t)8 * NP;    // 24*NP packed [B][HW][24]
  ushort* w7   = w5   + (size_t)24 * NP;   // 48*NP packed [B][HW][48]
  float* mask  = (float*)(w7 + (size_t)48 * NP);  // 3*NP f32
  float* conf  = mask + (size_t)3 * NP;    // 3*NP f32
  float* hA    = conf + (size_t)3 * NP;    // 6*NP f32 ping-pong
  float* hns   = hA   + (size_t)6 * NP;    // 3*NP f32
  ushort* wp   = (ushort*)(hns + (size_t)3 * NP); // PREP_N prepped weights

  dim3 blk(256);
  dim3 gc(W_ / 64, H_ / 4, B_);   // 19 x 64 x 2
  int ge = NP / 256;
  constexpr int PB = 2 * WP * 4 + 2 * (HP - 2) * 4;
  int gz = (2 * PB + 255) / 256;
  int gp = (PREP_N + 255) / 256;

  prep_k<<<gp, blk, 0, stream>>>(k3w1, k5w1, k7w1, k3w2, k5w2, k7w2,
                                 mw1, cw1, tw1, mw2, cw2, tw2, wp);
  zring_k<<<gz, blk, 0, stream>>>(hPb);

  // kernel-generator branches: split-precision conv1 + conv2
  convs1<<<gc, blk, 0, stream>>>(fout, wp + PW1_K3, k3s1, k3b1, hPb);
  convs2<1, 4><<<gc, blk, 0, stream>>>(hPb, wp + PW2_K3, k3s2, k3b2, w3, 8);
  convs1<<<gc, blk, 0, stream>>>(fout, wp + PW1_K5, k5s1, k5b1, hPb);
  convs2<2, 4><<<gc, blk, 0, stream>>>(hPb, wp + PW2_K5, k5s2, k5b2, w5, 24);
  convs1<<<gc, blk, 0, stream>>>(fout, wp + PW1_K7, k7s1, k7b1, hPb);
  convs2<3, 3><<<gc, blk, 0, stream>>>(hPb, wp + PW2_K7, k7s2, k7b2, w7, 48);

  // mask branch
  conv1p<0, 4><<<gc, blk, 0, stream>>>(fout, nullptr, wp + PP1_M, nullptr, ms1, mb1, hPb);
  conv2g<2><<<gc, blk, 0, stream>>>(hPb, wp + PG2_M, mbias2, h0, nullptr, mask);

  // confidence branch
  conv1p<0, 4><<<gc, blk, 0, stream>>>(fout, nullptr, wp + PP1_C, nullptr, cs1, cb1, hPb);
  conv2g<3><<<gc, blk, 0, stream>>>(hPb, wp + PG2_C, cbias2, nullptr, nullptr, conf);

  // propagation
  float* h3c = hA + (size_t)0 * NP; float* h3n = hA + (size_t)1 * NP;
  float* h5c = hA + (size_t)2 * NP; float* h5n = hA + (size_t)3 * NP;
  float* h7c = hA + (size_t)4 * NP; float* h7n = hA + (size_t)5 * NP;

  init_k<<<ge, blk, 0, stream>>>(hn, h3c, h5c, h7c, hns);
  for (int i = 0; i < 6; ++i) {
    int chn = (i == 2) ? 1 : ((i == 5) ? 2 : -1);
    iterate_k<<<ge, blk, 0, stream>>>(h3c, h5c, h7c, h3n, h5n, h7n,
                                      w3, w5, w7, mask, h0, hns, chn, conf);
    float* t;
    t = h3c; h3c = h3n; h3n = t;
    t = h5c; h5c = h5n; h5n = t;
    t = h7c; h7c = h7n; h7n = t;
  }

  // final temporal-weight branch
  conv1p<1, 3><<<gc, blk, 0, stream>>>(fout, hns, wp + PP1_T, wp + PP1T2, ts1, tb1, hPb);
  conv2g<4><<<gc, blk, 0, stream>>>(hPb, wp + PG2_T, tbias2, nullptr, hns, out);
}

// Round 21
// 870.202 us; speedup vs baseline: 1.1449x; 1.0334x over previous
//
#include <hip/hip_runtime.h>
#include <hip/hip_bf16.h>

constexpr int B_ = 2, H_ = 256, W_ = 1216;
constexpr int HW = H_ * W_;          // 311296
constexpr int NP = B_ * HW;          // 622592
constexpr int WP = W_ + 2;           // 1218 padded width
constexpr int HP = H_ + 2;           // 258  padded height
constexpr int HWP = HP * WP;         // 314244
constexpr float EPS_ = 1e-6f;

// prepped-weight region offsets (ushort units)
constexpr int PW1_K3 = 0;                    // [2][9][32][32] hi/lo, stride 18432/branch
constexpr int PW1_K5 = 18432;
constexpr int PW1_K7 = 36864;
constexpr int PW2_K3 = 55296;                // [2][9][16][32]
constexpr int PW2_K5 = 64512;                // [2][9][32][32]
constexpr int PW2_K7 = 82944;                // [2][9][48][32]
constexpr int PP1_M  = 110592;               // [9][32][32] plain, stride 9216/branch
constexpr int PP1_C  = 119808;
constexpr int PP1_T  = 129024;
constexpr int PP1T2  = 138240;               // [9][32][8]
constexpr int PG2_M  = 140544;               // [9][16][32] plain
constexpr int PG2_C  = 145152;
constexpr int PG2_T  = 149760;
constexpr int PREP_N = 154368;

typedef __bf16 bfrag __attribute__((ext_vector_type(8)));
typedef float f4 __attribute__((ext_vector_type(4)));

union BU { uint4 u; bfrag f; };
union U8 { uint4 u; ushort s[8]; };

__device__ __forceinline__ ushort f2b(float x) {
  uint u = __float_as_uint(x);
  u += 0x7fffu + ((u >> 16) & 1u);
  return (ushort)(u >> 16);
}
__device__ __forceinline__ float b2f(ushort u) {
  return __uint_as_float(((uint)u) << 16);
}

// ---------------------------------------------------------------------------
// One-shot weight prep (R6 exact).
// ---------------------------------------------------------------------------
__global__ __launch_bounds__(256)
void prep_k(const float* __restrict__ k3w1, const float* __restrict__ k5w1,
            const float* __restrict__ k7w1, const float* __restrict__ k3w2,
            const float* __restrict__ k5w2, const float* __restrict__ k7w2,
            const float* __restrict__ mw1, const float* __restrict__ cw1,
            const float* __restrict__ tw1, const float* __restrict__ mw2,
            const float* __restrict__ cw2, const float* __restrict__ tw2,
            ushort* __restrict__ wp)
{
  int i = blockIdx.x * 256 + threadIdx.x;
  if (i >= PREP_N) return;
  ushort outv;
  if (i < PW2_K3) {                       // conv1 chains hi/lo [c][2][9][32][32]
    int c = i / 18432, r = i % 18432;
    const float* src = (c == 0) ? k3w1 : (c == 1) ? k5w1 : k7w1;
    int ci = r & 31; int t1 = r >> 5;
    int co = t1 & 31; int t2 = t1 >> 5;
    int tap = t2 % 9, half = t2 / 9;
    float v = src[(co * 32 + ci) * 9 + tap];
    ushort hi = f2b(v);
    outv = half ? f2b(v - b2f(hi)) : hi;
  } else if (i < PP1_M) {                 // conv2 chains [2][9][NM16][32]
    int r = i - PW2_K3;
    const float* src; int NM16, CO;
    if (r < 9216)       { src = k3w2; NM16 = 16; CO = 8; }
    else if (r < 27648) { src = k5w2; NM16 = 32; CO = 24; r -= 9216; }
    else                { src = k7w2; NM16 = 48; CO = 48; r -= 27648; }
    int ci = r & 31; int t1 = r >> 5;
    int co = t1 % NM16; int t2 = t1 / NM16;
    int tap = t2 % 9, half = t2 / 9;
    if (co < CO) {
      float v = src[(co * 32 + ci) * 9 + tap];
      ushort hi = f2b(v);
      outv = half ? f2b(v - b2f(hi)) : hi;
    } else outv = 0;
  } else if (i < PP1T2) {                 // conv1p plain [c][9][32][32]
    int r = i - PP1_M;
    int c = r / 9216; r %= 9216;
    const float* src = (c == 0) ? mw1 : (c == 1) ? cw1 : tw1;
    int CIN = (c == 2) ? 35 : 32;
    int ci = r & 31; int t1 = r >> 5;
    int co = t1 & 31, tap = t1 >> 5;
    outv = f2b(src[(co * CIN + ci) * 9 + tap]);
  } else if (i < PG2_M) {                 // t-branch extra K [9][32][8]
    int r = i - PP1T2;
    int c8 = r & 7; int t1 = r >> 3;
    int co = t1 & 31, tap = t1 >> 5;
    int cc = (c8 < 3) ? c8 : ((c8 < 6) ? c8 - 3 : -1);
    outv = (cc >= 0) ? f2b(tw1[(co * 35 + 32 + cc) * 9 + tap]) : (ushort)0;
  } else {                                // conv2g [c][9][16][32]
    int r = i - PG2_M;
    int c = r / 4608; r %= 4608;
    const float* src = (c == 0) ? mw2 : (c == 1) ? cw2 : tw2;
    int ci = r & 31; int t1 = r >> 5;
    int co = t1 & 15, tap = t1 >> 4;
    outv = (co < 3) ? f2b(src[(co * 32 + ci) * 9 + tap]) : (ushort)0;
  }
  wp[i] = outv;
}

// ---------------------------------------------------------------------------
// Zero the pad ring of 3 hP plane-pairs (6 sub-planes). (R10 version, ran OK)
// ---------------------------------------------------------------------------
__global__ __launch_bounds__(256)
void zring_k(ushort* __restrict__ hP) {
  constexpr int PB = 2 * WP * 4 + 2 * (HP - 2) * 4;   // uint4 units per sub-plane
  int i = blockIdx.x * 256 + threadIdx.x;
  if (i >= 6 * PB) return;
  int bp = i / PB, r = i % PB;
  size_t idx;
  if (r < WP * 4) idx = (size_t)r;
  else if (r < 2 * WP * 4) idx = (size_t)(HP - 1) * WP * 4 + (r - WP * 4);
  else {
    int q = r - 2 * WP * 4;
    int row = q >> 3, k = q & 7;
    int col = (k < 4) ? k : (WP - 1) * 4 + (k - 4);
    idx = (size_t)(row + 1) * WP * 4 + col;
  }
  *(uint4*)&hP[(size_t)bp * HWP * 32 + idx * 8] = uint4{0, 0, 0, 0};
}

// ---------------------------------------------------------------------------
// BATCHED split-precision conv1 (all 3 w-chains in one dispatch):
// blockIdx.z = br*2 + b. Per-block code identical to R6 convs1; each branch
// writes its OWN hP plane (no serialization via hPb reuse -> 3x blocks in
// flight, testing the parallelism-starved-BW theory).
// ---------------------------------------------------------------------------
__global__ __launch_bounds__(256, 3)
void convs1z(const float* __restrict__ xf, const ushort* __restrict__ wp,
             const float* __restrict__ s3, const float* __restrict__ b3,
             const float* __restrict__ s5, const float* __restrict__ b5,
             const float* __restrict__ s7, const float* __restrict__ b7,
             ushort* __restrict__ outh)
{
  __shared__ ushort xl[25344];   // hi [0,12672) | lo [12672,25344)

  const int tid = threadIdx.x;
  const int lane = tid & 63;
  const int wid = tid >> 6;
  const int x0 = blockIdx.x * 64, y0 = blockIdx.y * 4;
  const int zz = blockIdx.z;            // 0..5
  const int br = zz >> 1, b = zz & 1;
  const ushort* wpb = wp + br * 18432;
  const float* scale = (br == 0) ? s3 : (br == 1) ? s5 : s7;
  const float* bias  = (br == 0) ? b3 : (br == 1) ? b5 : b7;
  ushort* outp = outh + (size_t)br * 2 * HWP * 32;

  for (int i = tid; i < 396 * 4; i += 256) {
    int oct = i & 3, rest = i >> 2;
    int xx = rest % 66, rr = rest / 66;
    int yy = y0 - 1 + rr, x = x0 - 1 + xx;
    uint4 vh = {0, 0, 0, 0}, vl = {0, 0, 0, 0};
    if ((unsigned)yy < (unsigned)H_ && (unsigned)x < (unsigned)W_) {
      const float* src = xf + ((size_t)b * 32 + oct * 8) * HW + (size_t)yy * W_ + x;
      uint uh[4], ul[4];
#pragma unroll
      for (int j = 0; j < 4; ++j) {
        float a = src[(size_t)(2 * j + 0) * HW];
        float c = src[(size_t)(2 * j + 1) * HW];
        ushort ah = f2b(a), ch = f2b(c);
        ushort al = f2b(a - b2f(ah)), cl = f2b(c - b2f(ch));
        uh[j] = (uint)ah | ((uint)ch << 16);
        ul[j] = (uint)al | ((uint)cl << 16);
      }
      vh = uint4{uh[0], uh[1], uh[2], uh[3]};
      vl = uint4{ul[0], ul[1], ul[2], ul[3]};
    }
    *(uint4*)&xl[rest * 32 + oct * 8] = vh;
    *(uint4*)&xl[12672 + rest * 32 + oct * 8] = vl;
  }
  __syncthreads();

  const int n = lane & 15, quad = lane >> 4;

  f4 acc[4][2];
#pragma unroll
  for (int tu = 0; tu < 4; ++tu)
#pragma unroll
    for (int mt = 0; mt < 2; ++mt) acc[tu][mt] = f4{0.f, 0.f, 0.f, 0.f};

#pragma unroll
  for (int tap = 0; tap < 9; ++tap) {
    int dy = tap / 3, dx = tap % 3;
    bfrag avhi[2], avlo[2];
#pragma unroll
    for (int mt = 0; mt < 2; ++mt) {
      avhi[mt] = *(const bfrag*)&wpb[((tap * 32) + mt * 16 + n) * 32 + quad * 8];
      avlo[mt] = *(const bfrag*)&wpb[(((9 + tap) * 32) + mt * 16 + n) * 32 + quad * 8];
    }
#pragma unroll
    for (int tu = 0; tu < 4; ++tu) {
      int t = wid + tu * 4;
      int r = t >> 2, g = t & 3;
      int pix = (r + dy) * 66 + g * 16 + n + dx;
      bfrag bhi = *(const bfrag*)&xl[pix * 32 + quad * 8];
      bfrag blo = *(const bfrag*)&xl[12672 + pix * 32 + quad * 8];
#pragma unroll
      for (int mt = 0; mt < 2; ++mt) {
        acc[tu][mt] = __builtin_amdgcn_mfma_f32_16x16x32_bf16(avhi[mt], bhi, acc[tu][mt], 0, 0, 0);
        acc[tu][mt] = __builtin_amdgcn_mfma_f32_16x16x32_bf16(avhi[mt], blo, acc[tu][mt], 0, 0, 0);
        acc[tu][mt] = __builtin_amdgcn_mfma_f32_16x16x32_bf16(avlo[mt], bhi, acc[tu][mt], 0, 0, 0);
      }
    }
  }

#pragma unroll
  for (int tu = 0; tu < 4; ++tu) {
    int t = wid + tu * 4;
    int r = t >> 2, g = t & 3;
    int gx = x0 + g * 16 + n, gy = y0 + r;
    size_t bpix = (size_t)b * HWP + (size_t)(gy + 1) * WP + (gx + 1);
#pragma unroll
    for (int mt = 0; mt < 2; ++mt) {
      int cob = mt * 16 + quad * 4;
      float v0 = fmaxf(acc[tu][mt][0] * scale[cob + 0] + bias[cob + 0], 0.f);
      float v1 = fmaxf(acc[tu][mt][1] * scale[cob + 1] + bias[cob + 1], 0.f);
      float v2 = fmaxf(acc[tu][mt][2] * scale[cob + 2] + bias[cob + 2], 0.f);
      float v3 = fmaxf(acc[tu][mt][3] * scale[cob + 3] + bias[cob + 3], 0.f);
      uint u0 = (uint)f2b(v0) | ((uint)f2b(v1) << 16);
      uint u1 = (uint)f2b(v2) | ((uint)f2b(v3) << 16);
      *(uint2*)&outp[bpix * 32 + cob] = uint2{u0, u1};
    }
  }
}

// ---------------------------------------------------------------------------
// Split-precision conv2 (R6 exact): LDS-staged B tile, tap-double-buffered
// hi/lo weights, pixel-major packed output [B][HW][CO].
// ---------------------------------------------------------------------------
template<int nM, int MINW>
__global__ __launch_bounds__(256, MINW)
void convs2(const ushort* __restrict__ hP, const ushort* __restrict__ wp,
            const float* __restrict__ scale, const float* __restrict__ bias,
            ushort* __restrict__ outw, int CO)
{
  __shared__ ushort xl[12672];

  constexpr int NM16 = nM * 16;
  const int tid = threadIdx.x;
  const int lane = tid & 63;
  const int wid = tid >> 6;
  const int x0 = blockIdx.x * 64, y0 = blockIdx.y * 4, b = blockIdx.z;
  const ushort* hb = hP + (size_t)b * HWP * 32;

  for (int i = tid; i < 396 * 4; i += 256) {
    int oct = i & 3, rest = i >> 2;
    int xx = rest % 66, rr = rest / 66;
    *(uint4*)&xl[rest * 32 + oct * 8] =
        *(const uint4*)&hb[((size_t)(y0 + rr) * WP + (x0 + xx)) * 32 + oct * 8];
  }

  const int n = lane & 15, quad = lane >> 4;

  f4 acc[4][nM];
#pragma unroll
  for (int tu = 0; tu < 4; ++tu)
#pragma unroll
    for (int mt = 0; mt < nM; ++mt) acc[tu][mt] = f4{0.f, 0.f, 0.f, 0.f};

  bfrag whi[2][nM], wlo[2][nM];
#pragma unroll
  for (int mt = 0; mt < nM; ++mt) {
    whi[0][mt] = *(const bfrag*)&wp[(mt * 16 + n) * 32 + quad * 8];
    wlo[0][mt] = *(const bfrag*)&wp[((9 * NM16) + mt * 16 + n) * 32 + quad * 8];
  }
  __syncthreads();

#pragma unroll
  for (int tap = 0; tap < 9; ++tap) {
    const int dy = tap / 3, dx = tap % 3;
    const int cur = tap & 1, nxt = cur ^ 1;
    if (tap < 8) {
#pragma unroll
      for (int mt = 0; mt < nM; ++mt) {
        whi[nxt][mt] = *(const bfrag*)&wp[(((tap + 1) * NM16) + mt * 16 + n) * 32 + quad * 8];
        wlo[nxt][mt] = *(const bfrag*)&wp[(((9 + tap + 1) * NM16) + mt * 16 + n) * 32 + quad * 8];
      }
    }
#pragma unroll
    for (int tu = 0; tu < 4; ++tu) {
      int t = wid + tu * 4;
      int r = t >> 2, g = t & 3;
      int pix = (r + dy) * 66 + g * 16 + n + dx;
      bfrag bv = *(const bfrag*)&xl[pix * 32 + quad * 8];
#pragma unroll
      for (int mt = 0; mt < nM; ++mt) {
        acc[tu][mt] = __builtin_amdgcn_mfma_f32_16x16x32_bf16(whi[cur][mt], bv, acc[tu][mt], 0, 0, 0);
        acc[tu][mt] = __builtin_amdgcn_mfma_f32_16x16x32_bf16(wlo[cur][mt], bv, acc[tu][mt], 0, 0, 0);
      }
    }
  }

#pragma unroll
  for (int tu = 0; tu < 4; ++tu) {
    int t = wid + tu * 4;
    int r = t >> 2, g = t & 3;
    int gx = x0 + g * 16 + n, gy = y0 + r;
    size_t gpix = (size_t)gy * W_ + gx;

    float vs[nM][4];
    float pa = 0.f;
#pragma unroll
    for (int mt = 0; mt < nM; ++mt)
#pragma unroll
      for (int rg = 0; rg < 4; ++rg) {
        int co = mt * 16 + quad * 4 + rg;
        float v = (co < CO) ? acc[tu][mt][rg] * scale[co] + bias[co] : 0.f;
        vs[mt][rg] = v;
        pa += fabsf(v);
      }
    pa += __shfl_xor(pa, 16);
    pa += __shfl_xor(pa, 32);
    float inv = 1.f / (pa + EPS_);

    size_t base = ((size_t)b * HW + gpix) * (size_t)CO;
#pragma unroll
    for (int mt = 0; mt < nM; ++mt) {
      int cob = mt * 16 + quad * 4;
      if (cob < CO) {
        uint u0 = (uint)f2b(vs[mt][0] * inv) | ((uint)f2b(vs[mt][1] * inv) << 16);
        uint u1 = (uint)f2b(vs[mt][2] * inv) | ((uint)f2b(vs[mt][3] * inv) << 16);
        *(uint2*)&outw[base + cob] = uint2{u0, u1};
      }
    }
  }
}

// ---------------------------------------------------------------------------
// BATCHED plain conv1 for mask+conf (one dispatch, blockIdx.z = br*2 + b).
// Per-block code identical to R6 conv1p<0,*>; per-branch weights/out plane.
// ---------------------------------------------------------------------------
__global__ __launch_bounds__(256, 4)
void conv1pz(const float* __restrict__ xf, const ushort* __restrict__ wp,
             const float* __restrict__ sm, const float* __restrict__ bm,
             const float* __restrict__ sc, const float* __restrict__ bc,
             ushort* __restrict__ outh)
{
  __shared__ ushort xl[396 * 32];

  const int tid = threadIdx.x;
  const int lane = tid & 63;
  const int wid = tid >> 6;
  const int x0 = blockIdx.x * 64, y0 = blockIdx.y * 4;
  const int zz = blockIdx.z;            // 0..3
  const int br = zz >> 1, b = zz & 1;
  const ushort* wpb = wp + br * 9216;
  const float* scale = br ? sc : sm;
  const float* bias  = br ? bc : bm;
  ushort* outp = outh + (size_t)br * 2 * HWP * 32;

  for (int i = tid; i < 396 * 4; i += 256) {
    int oct = i & 3, rest = i >> 2;
    int xx = rest % 66, rr = rest / 66;
    int yy = y0 - 1 + rr, x = x0 - 1 + xx;
    uint4 v = {0, 0, 0, 0};
    if ((unsigned)yy < (unsigned)H_ && (unsigned)x < (unsigned)W_) {
      const float* src = xf + ((size_t)b * 32 + oct * 8) * HW + (size_t)yy * W_ + x;
      uint u[4];
#pragma unroll
      for (int j = 0; j < 4; ++j) {
        float a = src[(size_t)(2 * j + 0) * HW];
        float c = src[(size_t)(2 * j + 1) * HW];
        u[j] = (uint)f2b(a) | ((uint)f2b(c) << 16);
      }
      v = uint4{u[0], u[1], u[2], u[3]};
    }
    *(uint4*)&xl[rest * 32 + oct * 8] = v;
  }
  __syncthreads();

  const int n = lane & 15, quad = lane >> 4;

  f4 acc[4][2];
#pragma unroll
  for (int tu = 0; tu < 4; ++tu)
#pragma unroll
    for (int mt = 0; mt < 2; ++mt) acc[tu][mt] = f4{0.f, 0.f, 0.f, 0.f};

#pragma unroll
  for (int tap = 0; tap < 9; ++tap) {
    int dy = tap / 3, dx = tap % 3;
    bfrag av[2];
#pragma unroll
    for (int mt = 0; mt < 2; ++mt)
      av[mt] = *(const bfrag*)&wpb[((tap * 32) + mt * 16 + n) * 32 + quad * 8];
#pragma unroll
    for (int tu = 0; tu < 4; ++tu) {
      int t = wid + tu * 4;
      int r = t >> 2, g = t & 3;
      int pix = (r + dy) * 66 + g * 16 + n + dx;
      bfrag bv = *(const bfrag*)&xl[pix * 32 + quad * 8];
#pragma unroll
      for (int mt = 0; mt < 2; ++mt)
        acc[tu][mt] = __builtin_amdgcn_mfma_f32_16x16x32_bf16(av[mt], bv, acc[tu][mt], 0, 0, 0);
    }
  }

#pragma unroll
  for (int tu = 0; tu < 4; ++tu) {
    int t = wid + tu * 4;
    int r = t >> 2, g = t & 3;
    int gx = x0 + g * 16 + n, gy = y0 + r;
    size_t bpix = (size_t)b * HWP + (size_t)(gy + 1) * WP + (gx + 1);
#pragma unroll
    for (int mt = 0; mt < 2; ++mt) {
      int cob = mt * 16 + quad * 4;
      float v0 = fmaxf(acc[tu][mt][0] * scale[cob + 0] + bias[cob + 0], 0.f);
      float v1 = fmaxf(acc[tu][mt][1] * scale[cob + 1] + bias[cob + 1], 0.f);
      float v2 = fmaxf(acc[tu][mt][2] * scale[cob + 2] + bias[cob + 2], 0.f);
      float v3 = fmaxf(acc[tu][mt][3] * scale[cob + 3] + bias[cob + 3], 0.f);
      uint u0 = (uint)f2b(v0) | ((uint)f2b(v1) << 16);
      uint u1 = (uint)f2b(v2) | ((uint)f2b(v3) << 16);
      *(uint2*)&outp[bpix * 32 + cob] = uint2{u0, u1};
    }
  }
}

// ---------------------------------------------------------------------------
// Plain bf16 conv1 (t-branch, KB2=1) — R6 exact.
// ---------------------------------------------------------------------------
template<int KB2, int MINW>
__global__ __launch_bounds__(256, MINW)
void conv1p(const float* __restrict__ xf, const float* __restrict__ hnsp,
            const ushort* __restrict__ wp, const ushort* __restrict__ wp2,
            const float* __restrict__ scale, const float* __restrict__ bias,
            ushort* __restrict__ outh)
{
  __shared__ ushort xl[396 * 32];
  __shared__ ushort xl2[KB2 ? 396 * 8 : 8];

  const int tid = threadIdx.x;
  const int lane = tid & 63;
  const int wid = tid >> 6;
  const int x0 = blockIdx.x * 64, y0 = blockIdx.y * 4, b = blockIdx.z;

  if (KB2) {
    for (int i = tid; i < 396; i += 256) {
      int xx = i % 66, rr = i / 66;
      int yy = y0 - 1 + rr, x = x0 - 1 + xx;
      float v0 = 0.f, v1 = 0.f, v2 = 0.f;
      if ((unsigned)yy < (unsigned)H_ && (unsigned)x < (unsigned)W_) {
        size_t pix = (size_t)yy * W_ + x;
        v0 = hnsp[((size_t)b * 3 + 0) * HW + pix];
        v1 = hnsp[((size_t)b * 3 + 1) * HW + pix];
        v2 = hnsp[((size_t)b * 3 + 2) * HW + pix];
      }
      ushort h0b = f2b(v0), h1b = f2b(v1), h2b = f2b(v2);
      ushort l0 = f2b(v0 - b2f(h0b)), l1 = f2b(v1 - b2f(h1b)), l2 = f2b(v2 - b2f(h2b));
      uint u0 = (uint)h0b | ((uint)h1b << 16);
      uint u1 = (uint)h2b | ((uint)l0 << 16);
      uint u2 = (uint)l1 | ((uint)l2 << 16);
      *(uint4*)&xl2[i * 8] = uint4{u0, u1, u2, 0};
    }
  }
  for (int i = tid; i < 396 * 4; i += 256) {
    int oct = i & 3, rest = i >> 2;
    int xx = rest % 66, rr = rest / 66;
    int yy = y0 - 1 + rr, x = x0 - 1 + xx;
    uint4 v = {0, 0, 0, 0};
    if ((unsigned)yy < (unsigned)H_ && (unsigned)x < (unsigned)W_) {
      const float* src = xf + ((size_t)b * 32 + oct * 8) * HW + (size_t)yy * W_ + x;
      uint u[4];
#pragma unroll
      for (int j = 0; j < 4; ++j) {
        float a = src[(size_t)(2 * j + 0) * HW];
        float c = src[(size_t)(2 * j + 1) * HW];
        u[j] = (uint)f2b(a) | ((uint)f2b(c) << 16);
      }
      v = uint4{u[0], u[1], u[2], u[3]};
    }
    *(uint4*)&xl[rest * 32 + oct * 8] = v;
  }
  __syncthreads();

  const int n = lane & 15, quad = lane >> 4;

  f4 acc[4][2];
#pragma unroll
  for (int tu = 0; tu < 4; ++tu)
#pragma unroll
    for (int mt = 0; mt < 2; ++mt) acc[tu][mt] = f4{0.f, 0.f, 0.f, 0.f};

#pragma unroll
  for (int tap = 0; tap < 9; ++tap) {
    int dy = tap / 3, dx = tap % 3;
    bfrag av[2];
#pragma unroll
    for (int mt = 0; mt < 2; ++mt)
      av[mt] = *(const bfrag*)&wp[((tap * 32) + mt * 16 + n) * 32 + quad * 8];
    bfrag a2[KB2 ? 2 : 1];
    if (KB2) {
#pragma unroll
      for (int mt = 0; mt < 2; ++mt) {
        BU t; t.u = uint4{0, 0, 0, 0};
        if (lane < 16) t.f = *(const bfrag*)&wp2[(tap * 32 + mt * 16 + lane) * 8];
        a2[mt] = t.f;
      }
    }
#pragma unroll
    for (int tu = 0; tu < 4; ++tu) {
      int t = wid + tu * 4;
      int r = t >> 2, g = t & 3;
      int pix = (r + dy) * 66 + g * 16 + n + dx;
      bfrag bv = *(const bfrag*)&xl[pix * 32 + quad * 8];
#pragma unroll
      for (int mt = 0; mt < 2; ++mt)
        acc[tu][mt] = __builtin_amdgcn_mfma_f32_16x16x32_bf16(av[mt], bv, acc[tu][mt], 0, 0, 0);
      if (KB2) {
        BU t2; t2.u = uint4{0, 0, 0, 0};
        if (lane < 16) t2.f = *(const bfrag*)&xl2[pix * 8];
#pragma unroll
        for (int mt = 0; mt < 2; ++mt)
          acc[tu][mt] = __builtin_amdgcn_mfma_f32_16x16x32_bf16(a2[mt], t2.f, acc[tu][mt], 0, 0, 0);
      }
    }
  }

#pragma unroll
  for (int tu = 0; tu < 4; ++tu) {
    int t = wid + tu * 4;
    int r = t >> 2, g = t & 3;
    int gx = x0 + g * 16 + n, gy = y0 + r;
    size_t bpix = (size_t)b * HWP + (size_t)(gy + 1) * WP + (gx + 1);
#pragma unroll
    for (int mt = 0; mt < 2; ++mt) {
      int cob = mt * 16 + quad * 4;
      float v0 = fmaxf(acc[tu][mt][0] * scale[cob + 0] + bias[cob + 0], 0.f);
      float v1 = fmaxf(acc[tu][mt][1] * scale[cob + 1] + bias[cob + 1], 0.f);
      float v2 = fmaxf(acc[tu][mt][2] * scale[cob + 2] + bias[cob + 2], 0.f);
      float v3 = fmaxf(acc[tu][mt][3] * scale[cob + 3] + bias[cob + 3], 0.f);
      uint u0 = (uint)f2b(v0) | ((uint)f2b(v1) << 16);
      uint u1 = (uint)f2b(v2) | ((uint)f2b(v3) << 16);
      *(uint2*)&outh[bpix * 32 + cob] = uint2{u0, u1};
    }
  }
}

// ---------------------------------------------------------------------------
// Small conv2 (CO=3) — R6 exact.
// ---------------------------------------------------------------------------
template<int EPI>
__global__ __launch_bounds__(256, 4)
void conv2g(const ushort* __restrict__ hP, const ushort* __restrict__ wp,
            const float* __restrict__ bias, const float* __restrict__ h0,
            const float* __restrict__ hnsp, float* __restrict__ outf)
{
  __shared__ ushort xl[12672];

  const int tid = threadIdx.x;
  const int lane = tid & 63;
  const int wid = tid >> 6;
  const int x0 = blockIdx.x * 64, y0 = blockIdx.y * 4, b = blockIdx.z;
  const int n = lane & 15, quad = lane >> 4;
  const ushort* hb = hP + (size_t)b * HWP * 32;

  for (int i = tid; i < 396 * 4; i += 256) {
    int oct = i & 3, rest = i >> 2;
    int xx = rest % 66, rr = rest / 66;
    *(uint4*)&xl[rest * 32 + oct * 8] =
        *(const uint4*)&hb[((size_t)(y0 + rr) * WP + (x0 + xx)) * 32 + oct * 8];
  }

  bfrag av[9];
#pragma unroll
  for (int tap = 0; tap < 9; ++tap)
    av[tap] = *(const bfrag*)&wp[((tap * 16) + n) * 32 + quad * 8];

  f4 acc[4];
#pragma unroll
  for (int tu = 0; tu < 4; ++tu) acc[tu] = f4{0.f, 0.f, 0.f, 0.f};
  __syncthreads();

#pragma unroll
  for (int tap = 0; tap < 9; ++tap) {
    int dy = tap / 3, dx = tap % 3;
#pragma unroll
    for (int tu = 0; tu < 4; ++tu) {
      int t = wid + tu * 4;
      int r = t >> 2, g = t & 3;
      int pix = (r + dy) * 66 + g * 16 + n + dx;
      bfrag bv = *(const bfrag*)&xl[pix * 32 + quad * 8];
      acc[tu] = __builtin_amdgcn_mfma_f32_16x16x32_bf16(av[tap], bv, acc[tu], 0, 0, 0);
    }
  }

#pragma unroll
  for (int tu = 0; tu < 4; ++tu) {
    int t = wid + tu * 4;
    int r = t >> 2, g = t & 3;
    int gx = x0 + g * 16 + n, gy = y0 + r;
    size_t gpix = (size_t)gy * W_ + gx;
    size_t bpix = (size_t)b * HW + gpix;

    if constexpr (EPI == 2) {
      if (lane < 16) {
        float valid = (h0[bpix] > 0.001f) ? 1.f : 0.f;
#pragma unroll
        for (int rg = 0; rg < 3; ++rg) {
          float v = acc[tu][rg] + bias[rg];
          float sg = 1.f / (1.f + expf(-v));
          outf[((size_t)b * 3 + rg) * HW + gpix] = sg * valid;
        }
      }
    } else if constexpr (EPI == 3) {
      if (lane < 16) {
        float v0 = acc[tu][0] + bias[0];
        float v1 = acc[tu][1] + bias[1];
        float v2 = acc[tu][2] + bias[2];
        float m = fmaxf(v0, fmaxf(v1, v2));
        float e0 = expf(v0 - m), e1 = expf(v1 - m), e2 = expf(v2 - m);
        float inv = 1.f / (e0 + e1 + e2);
        outf[((size_t)b * 3 + 0) * HW + gpix] = e0 * inv;
        outf[((size_t)b * 3 + 1) * HW + gpix] = e1 * inv;
        outf[((size_t)b * 3 + 2) * HW + gpix] = e2 * inv;
      }
    } else if constexpr (EPI == 4) {
      if (lane < 16) {
        float v0 = acc[tu][0] + bias[0];
        float v1 = acc[tu][1] + bias[1];
        float v2 = acc[tu][2] + bias[2];
        float m = fmaxf(v0, fmaxf(v1, v2));
        float e0 = expf(v0 - m), e1 = expf(v1 - m), e2 = expf(v2 - m);
        float inv = 1.f / (e0 + e1 + e2);
        float a0 = hnsp[((size_t)b * 3 + 0) * HW + gpix];
        float a1 = hnsp[((size_t)b * 3 + 1) * HW + gpix];
        float a2v = hnsp[((size_t)b * 3 + 2) * HW + gpix];
        outf[bpix] = (e0 * a0 + e1 * a1 + e2 * a2v) * inv;
      }
    }
  }
}

// ---------------------------------------------------------------------------
__global__ __launch_bounds__(256)
void init_k(const float* __restrict__ hn, float* __restrict__ h3,
            float* __restrict__ h5, float* __restrict__ h7,
            float* __restrict__ hns)
{
  int t = blockIdx.x * 256 + threadIdx.x;
  if (t >= NP) return;
  float v = hn[t];
  h3[t] = v; h5[t] = v; h7[t] = v;
  int b = t / HW, rem = t - b * HW;
  hns[(size_t)b * 3 * HW + rem] = v;
}

// ---------------------------------------------------------------------------
// Propagation step — R6 exact.
// ---------------------------------------------------------------------------
__global__ __launch_bounds__(256)
void iterate_k(const float* __restrict__ h3i, const float* __restrict__ h5i,
               const float* __restrict__ h7i,
               float* __restrict__ h3o, float* __restrict__ h5o,
               float* __restrict__ h7o,
               const ushort* __restrict__ w3, const ushort* __restrict__ w5,
               const ushort* __restrict__ w7,
               const float* __restrict__ mask, const float* __restrict__ h0,
               float* __restrict__ hns, int chn, const float* __restrict__ conf)
{
  int t = blockIdx.x * 256 + threadIdx.x;
  if (t >= NP) return;
  int b = t / HW;
  int rem = t - b * HW;
  int y = rem / W_;
  int x = rem - y * W_;
  size_t pb = (size_t)b * HW;

  float h0v = h0[t];

  U8 a3; a3.u = *(const uint4*)&w3[((size_t)b * HW + rem) * 8];
  float s3 = 0.f, ws3 = 0.f;
#pragma unroll
  for (int p = 0; p < 8; ++p) {
    int tap = (p < 4) ? p : p + 1;
    int dy = tap / 3 - 1, dx = tap % 3 - 1;
    int yy = y + dy, xx = x + dx;
    float hv = ((unsigned)yy < (unsigned)H_ && (unsigned)xx < (unsigned)W_)
                   ? h3i[pb + yy * W_ + xx] : 0.f;
    float wv = b2f(a3.s[p]);
    ws3 += wv;
    s3 += wv * hv;
  }
  s3 += (1.f - ws3) * h3i[t];
  float m3 = mask[(size_t)(b * 3 + 0) * HW + rem];
  float n3 = (1.f - m3) * s3 + m3 * h0v;
  h3o[t] = n3;

  U8 a5[3];
  {
    const ushort* w5r = w5 + ((size_t)b * HW + rem) * 24;
#pragma unroll
    for (int q = 0; q < 3; ++q) a5[q].u = *(const uint4*)(w5r + q * 8);
  }
  float s5 = 0.f, ws5 = 0.f;
#pragma unroll
  for (int p = 0; p < 24; ++p) {
    int tap = (p < 12) ? p : p + 1;
    int dy = tap / 5 - 2, dx = tap % 5 - 2;
    int yy = y + dy, xx = x + dx;
    float hv = ((unsigned)yy < (unsigned)H_ && (unsigned)xx < (unsigned)W_)
                   ? h5i[pb + yy * W_ + xx] : 0.f;
    float wv = b2f(a5[p >> 3].s[p & 7]);
    ws5 += wv;
    s5 += wv * hv;
  }
  s5 += (1.f - ws5) * h5i[t];
  float m5 = mask[(size_t)(b * 3 + 1) * HW + rem];
  float n5 = (1.f - m5) * s5 + m5 * h0v;
  h5o[t] = n5;

  U8 a7[6];
  {
    const ushort* w7r = w7 + ((size_t)b * HW + rem) * 48;
#pragma unroll
    for (int q = 0; q < 6; ++q) a7[q].u = *(const uint4*)(w7r + q * 8);
  }
  float s7 = 0.f, ws7 = 0.f;
#pragma unroll
  for (int p = 0; p < 48; ++p) {
    int tap = (p < 24) ? p : p + 1;
    int dy = tap / 7 - 3, dx = tap % 7 - 3;
    int yy = y + dy, xx = x + dx;
    float hv = ((unsigned)yy < (unsigned)H_ && (unsigned)xx < (unsigned)W_)
                   ? h7i[pb + yy * W_ + xx] : 0.f;
    float wv = b2f(a7[p >> 3].s[p & 7]);
    ws7 += wv;
    s7 += wv * hv;
  }
  s7 += (1.f - ws7) * h7i[t];
  float m7 = mask[(size_t)(b * 3 + 2) * HW + rem];
  float n7 = (1.f - m7) * s7 + m7 * h0v;
  h7o[t] = n7;

  if (chn >= 0) {
    float c3 = conf[(size_t)(b * 3 + 0) * HW + rem];
    float c5 = conf[(size_t)(b * 3 + 1) * HW + rem];
    float c7 = conf[(size_t)(b * 3 + 2) * HW + rem];
    hns[(size_t)(b * 3 + chn) * HW + rem] = c3 * n3 + c5 * n5 + c7 * n7;
  }
}

extern "C" void kernel_launch(void* const* d_in, const int* in_sizes, int n_in,
                              void* d_out, int out_size, void* d_ws, size_t ws_size,
                              hipStream_t stream) {
  const float* fout = (const float*)d_in[0];
  const float* hn   = (const float*)d_in[1];
  const float* h0   = (const float*)d_in[2];
  const float* k3w1 = (const float*)d_in[3];
  const float* k3s1 = (const float*)d_in[4];
  const float* k3b1 = (const float*)d_in[5];
  const float* k3w2 = (const float*)d_in[6];
  const float* k3s2 = (const float*)d_in[7];
  const float* k3b2 = (const float*)d_in[8];
  const float* k5w1 = (const float*)d_in[9];
  const float* k5s1 = (const float*)d_in[10];
  const float* k5b1 = (const float*)d_in[11];
  const float* k5w2 = (const float*)d_in[12];
  const float* k5s2 = (const float*)d_in[13];
  const float* k5b2 = (const float*)d_in[14];
  const float* k7w1 = (const float*)d_in[15];
  const float* k7s1 = (const float*)d_in[16];
  const float* k7b1 = (const float*)d_in[17];
  const float* k7w2 = (const float*)d_in[18];
  const float* k7s2 = (const float*)d_in[19];
  const float* k7b2 = (const float*)d_in[20];
  const float* mw1  = (const float*)d_in[21];
  const float* ms1  = (const float*)d_in[22];
  const float* mb1  = (const float*)d_in[23];
  const float* mw2  = (const float*)d_in[24];
  const float* mbias2 = (const float*)d_in[25];
  const float* cw1  = (const float*)d_in[26];
  const float* cs1  = (const float*)d_in[27];
  const float* cb1  = (const float*)d_in[28];
  const float* cw2  = (const float*)d_in[29];
  const float* cbias2 = (const float*)d_in[30];
  const float* tw1  = (const float*)d_in[31];
  const float* ts1  = (const float*)d_in[32];
  const float* tb1  = (const float*)d_in[33];
  const float* tw2  = (const float*)d_in[34];
  const float* tbias2 = (const float*)d_in[35];

  float* out = (float*)d_out;

  // workspace: 3x hP plane-pairs + w planes bf16 + fp32 mask/conf/hA/hns + wprep
  size_t hP_elems = (size_t)2 * HWP * 32;            // ushorts per plane-pair
  size_t need = hP_elems * 3 * 2 + (size_t)NP * (80 * 2 + 15 * 4) + (size_t)PREP_N * 2;
  if (ws_size < need) return;
  ushort* hPb  = (ushort*)d_ws;            // 3 contiguous padded-NHWC bf16 plane-pairs
  ushort* w3   = hPb  + 3 * hP_elems;      // 8*NP  bf16 packed [B][HW][8]
  ushort* w5   = w3   + (size_t)8 * NP;    // 24*NP packed [B][HW][24]
  ushort* w7   = w5   + (size_t)24 * NP;   // 48*NP packed [B][HW][48]
  float* mask  = (float*)(w7 + (size_t)48 * NP);  // 3*NP f32
  float* conf  = mask + (size_t)3 * NP;    // 3*NP f32
  float* hA    = conf + (size_t)3 * NP;    // 6*NP f32 ping-pong
  float* hns   = hA   + (size_t)6 * NP;    // 3*NP f32
  ushort* wp   = (ushort*)(hns + (size_t)3 * NP); // PREP_N prepped weights

  dim3 blk(256);
  dim3 gc(W_ / 64, H_ / 4, B_);      // 19 x 64 x 2
  dim3 gc3(W_ / 64, H_ / 4, 6);      // batched: 3 branches x 2 batch
  dim3 gc2(W_ / 64, H_ / 4, 4);      // batched: 2 branches x 2 batch
  int ge = NP / 256;
  constexpr int PB = 2 * WP * 4 + 2 * (HP - 2) * 4;
  int gz = (6 * PB + 255) / 256;
  int gp = (PREP_N + 255) / 256;

  prep_k<<<gp, blk, 0, stream>>>(k3w1, k5w1, k7w1, k3w2, k5w2, k7w2,
                                 mw1, cw1, tw1, mw2, cw2, tw2, wp);
  zring_k<<<gz, blk, 0, stream>>>(hPb);

  // all 3 w-chain conv1s in ONE dispatch (per-branch hP planes)
  convs1z<<<gc3, blk, 0, stream>>>(fout, wp + PW1_K3,
                                   k3s1, k3b1, k5s1, k5b1, k7s1, k7b1, hPb);
  convs2<1, 4><<<gc, blk, 0, stream>>>(hPb,                wp + PW2_K3, k3s2, k3b2, w3, 8);
  convs2<2, 4><<<gc, blk, 0, stream>>>(hPb + hP_elems,     wp + PW2_K5, k5s2, k5b2, w5, 24);
  convs2<3, 3><<<gc, blk, 0, stream>>>(hPb + 2 * hP_elems, wp + PW2_K7, k7s2, k7b2, w7, 48);

  // mask+conf conv1 in ONE dispatch (planes 0,1; enqueued after convs2 reads)
  conv1pz<<<gc2, blk, 0, stream>>>(fout, wp + PP1_M, ms1, mb1, cs1, cb1, hPb);
  conv2g<2><<<gc, blk, 0, stream>>>(hPb,            wp + PG2_M, mbias2, h0, nullptr, mask);
  conv2g<3><<<gc, blk, 0, stream>>>(hPb + hP_elems, wp + PG2_C, cbias2, nullptr, nullptr, conf);

  // propagation
  float* h3c = hA + (size_t)0 * NP; float* h3n = hA + (size_t)1 * NP;
  float* h5c = hA + (size_t)2 * NP; float* h5n = hA + (size_t)3 * NP;
  float* h7c = hA + (size_t)4 * NP; float* h7n = hA + (size_t)5 * NP;

  init_k<<<ge, blk, 0, stream>>>(hn, h3c, h5c, h7c, hns);
  for (int i = 0; i < 6; ++i) {
    int chn = (i == 2) ? 1 : ((i == 5) ? 2 : -1);
    iterate_k<<<ge, blk, 0, stream>>>(h3c, h5c, h7c, h3n, h5n, h7n,
                                      w3, w5, w7, mask, h0, hns, chn, conf);
    float* t;
    t = h3c; h3c = h3n; h3n = t;
    t = h5c; h5c = h5n; h5n = t;
    t = h7c; h7c = h7n; h7n = t;
  }

  // final temporal-weight branch (plane 0, after conv2g mask read it)
  conv1p<1, 3><<<gc, blk, 0, stream>>>(fout, hns, wp + PP1_T, wp + PP1T2, ts1, tb1, hPb);
  conv2g<4><<<gc, blk, 0, stream>>>(hPb, wp + PG2_T, tbias2, nullptr, hns, out);
}

// Round 22
// 856.422 us; speedup vs baseline: 1.1633x; 1.0161x over previous
//
#include <hip/hip_runtime.h>
#include <hip/hip_bf16.h>

constexpr int B_ = 2, H_ = 256, W_ = 1216;
constexpr int HW = H_ * W_;          // 311296
constexpr int NP = B_ * HW;          // 622592
constexpr int WP = W_ + 2;           // 1218 padded width
constexpr int HP = H_ + 2;           // 258  padded height
constexpr int HWP = HP * WP;         // 314244
constexpr float EPS_ = 1e-6f;

// prepped-weight region offsets (ushort units)
constexpr int PW1_K3 = 0;                    // [2][9][32][32] hi/lo, stride 18432/branch
constexpr int PW1_K5 = 18432;
constexpr int PW1_K7 = 36864;
constexpr int PW2_K3 = 55296;                // [2][9][16][32]
constexpr int PW2_K5 = 64512;                // [2][9][32][32]
constexpr int PW2_K7 = 82944;                // [2][9][48][32]
constexpr int PP1_M  = 110592;               // [9][32][32] plain, stride 9216/branch
constexpr int PP1_C  = 119808;
constexpr int PP1_T  = 129024;
constexpr int PP1T2  = 138240;               // [9][32][8]
constexpr int PG2_M  = 140544;               // [9][16][32] plain, stride 4608/branch
constexpr int PG2_C  = 145152;
constexpr int PG2_T  = 149760;
constexpr int PREP_N = 154368;

typedef __bf16 bfrag __attribute__((ext_vector_type(8)));
typedef float f4 __attribute__((ext_vector_type(4)));

union BU { uint4 u; bfrag f; };
union U8 { uint4 u; ushort s[8]; };

__device__ __forceinline__ ushort f2b(float x) {
  uint u = __float_as_uint(x);
  u += 0x7fffu + ((u >> 16) & 1u);
  return (ushort)(u >> 16);
}
__device__ __forceinline__ float b2f(ushort u) {
  return __uint_as_float(((uint)u) << 16);
}

// ---------------------------------------------------------------------------
// One-shot weight prep (R6 exact).
// ---------------------------------------------------------------------------
__global__ __launch_bounds__(256)
void prep_k(const float* __restrict__ k3w1, const float* __restrict__ k5w1,
            const float* __restrict__ k7w1, const float* __restrict__ k3w2,
            const float* __restrict__ k5w2, const float* __restrict__ k7w2,
            const float* __restrict__ mw1, const float* __restrict__ cw1,
            const float* __restrict__ tw1, const float* __restrict__ mw2,
            const float* __restrict__ cw2, const float* __restrict__ tw2,
            ushort* __restrict__ wp)
{
  int i = blockIdx.x * 256 + threadIdx.x;
  if (i >= PREP_N) return;
  ushort outv;
  if (i < PW2_K3) {                       // conv1 chains hi/lo [c][2][9][32][32]
    int c = i / 18432, r = i % 18432;
    const float* src = (c == 0) ? k3w1 : (c == 1) ? k5w1 : k7w1;
    int ci = r & 31; int t1 = r >> 5;
    int co = t1 & 31; int t2 = t1 >> 5;
    int tap = t2 % 9, half = t2 / 9;
    float v = src[(co * 32 + ci) * 9 + tap];
    ushort hi = f2b(v);
    outv = half ? f2b(v - b2f(hi)) : hi;
  } else if (i < PP1_M) {                 // conv2 chains [2][9][NM16][32]
    int r = i - PW2_K3;
    const float* src; int NM16, CO;
    if (r < 9216)       { src = k3w2; NM16 = 16; CO = 8; }
    else if (r < 27648) { src = k5w2; NM16 = 32; CO = 24; r -= 9216; }
    else                { src = k7w2; NM16 = 48; CO = 48; r -= 27648; }
    int ci = r & 31; int t1 = r >> 5;
    int co = t1 % NM16; int t2 = t1 / NM16;
    int tap = t2 % 9, half = t2 / 9;
    if (co < CO) {
      float v = src[(co * 32 + ci) * 9 + tap];
      ushort hi = f2b(v);
      outv = half ? f2b(v - b2f(hi)) : hi;
    } else outv = 0;
  } else if (i < PP1T2) {                 // conv1p plain [c][9][32][32]
    int r = i - PP1_M;
    int c = r / 9216; r %= 9216;
    const float* src = (c == 0) ? mw1 : (c == 1) ? cw1 : tw1;
    int CIN = (c == 2) ? 35 : 32;
    int ci = r & 31; int t1 = r >> 5;
    int co = t1 & 31, tap = t1 >> 5;
    outv = f2b(src[(co * CIN + ci) * 9 + tap]);
  } else if (i < PG2_M) {                 // t-branch extra K [9][32][8]
    int r = i - PP1T2;
    int c8 = r & 7; int t1 = r >> 3;
    int co = t1 & 31, tap = t1 >> 5;
    int cc = (c8 < 3) ? c8 : ((c8 < 6) ? c8 - 3 : -1);
    outv = (cc >= 0) ? f2b(tw1[(co * 35 + 32 + cc) * 9 + tap]) : (ushort)0;
  } else {                                // conv2g [c][9][16][32]
    int r = i - PG2_M;
    int c = r / 4608; r %= 4608;
    const float* src = (c == 0) ? mw2 : (c == 1) ? cw2 : tw2;
    int ci = r & 31; int t1 = r >> 5;
    int co = t1 & 15, tap = t1 >> 4;
    outv = (co < 3) ? f2b(src[(co * 32 + ci) * 9 + tap]) : (ushort)0;
  }
  wp[i] = outv;
}

// ---------------------------------------------------------------------------
// Zero the pad ring of 3 hP plane-pairs (6 sub-planes).
// ---------------------------------------------------------------------------
__global__ __launch_bounds__(256)
void zring_k(ushort* __restrict__ hP) {
  constexpr int PB = 2 * WP * 4 + 2 * (HP - 2) * 4;   // uint4 units per sub-plane
  int i = blockIdx.x * 256 + threadIdx.x;
  if (i >= 6 * PB) return;
  int bp = i / PB, r = i % PB;
  size_t idx;
  if (r < WP * 4) idx = (size_t)r;
  else if (r < 2 * WP * 4) idx = (size_t)(HP - 1) * WP * 4 + (r - WP * 4);
  else {
    int q = r - 2 * WP * 4;
    int row = q >> 3, k = q & 7;
    int col = (k < 4) ? k : (WP - 1) * 4 + (k - 4);
    idx = (size_t)(row + 1) * WP * 4 + col;
  }
  *(uint4*)&hP[(size_t)bp * HWP * 32 + idx * 8] = uint4{0, 0, 0, 0};
}

// ---------------------------------------------------------------------------
// BATCHED split-precision conv1 (all 3 w-chains in one dispatch). (R21, WIN)
// ---------------------------------------------------------------------------
__global__ __launch_bounds__(256, 3)
void convs1z(const float* __restrict__ xf, const ushort* __restrict__ wp,
             const float* __restrict__ s3, const float* __restrict__ b3,
             const float* __restrict__ s5, const float* __restrict__ b5,
             const float* __restrict__ s7, const float* __restrict__ b7,
             ushort* __restrict__ outh)
{
  __shared__ ushort xl[25344];   // hi [0,12672) | lo [12672,25344)

  const int tid = threadIdx.x;
  const int lane = tid & 63;
  const int wid = tid >> 6;
  const int x0 = blockIdx.x * 64, y0 = blockIdx.y * 4;
  const int zz = blockIdx.z;            // 0..5
  const int br = zz >> 1, b = zz & 1;
  const ushort* wpb = wp + br * 18432;
  const float* scale = (br == 0) ? s3 : (br == 1) ? s5 : s7;
  const float* bias  = (br == 0) ? b3 : (br == 1) ? b5 : b7;
  ushort* outp = outh + (size_t)br * 2 * HWP * 32;

  for (int i = tid; i < 396 * 4; i += 256) {
    int oct = i & 3, rest = i >> 2;
    int xx = rest % 66, rr = rest / 66;
    int yy = y0 - 1 + rr, x = x0 - 1 + xx;
    uint4 vh = {0, 0, 0, 0}, vl = {0, 0, 0, 0};
    if ((unsigned)yy < (unsigned)H_ && (unsigned)x < (unsigned)W_) {
      const float* src = xf + ((size_t)b * 32 + oct * 8) * HW + (size_t)yy * W_ + x;
      uint uh[4], ul[4];
#pragma unroll
      for (int j = 0; j < 4; ++j) {
        float a = src[(size_t)(2 * j + 0) * HW];
        float c = src[(size_t)(2 * j + 1) * HW];
        ushort ah = f2b(a), ch = f2b(c);
        ushort al = f2b(a - b2f(ah)), cl = f2b(c - b2f(ch));
        uh[j] = (uint)ah | ((uint)ch << 16);
        ul[j] = (uint)al | ((uint)cl << 16);
      }
      vh = uint4{uh[0], uh[1], uh[2], uh[3]};
      vl = uint4{ul[0], ul[1], ul[2], ul[3]};
    }
    *(uint4*)&xl[rest * 32 + oct * 8] = vh;
    *(uint4*)&xl[12672 + rest * 32 + oct * 8] = vl;
  }
  __syncthreads();

  const int n = lane & 15, quad = lane >> 4;

  f4 acc[4][2];
#pragma unroll
  for (int tu = 0; tu < 4; ++tu)
#pragma unroll
    for (int mt = 0; mt < 2; ++mt) acc[tu][mt] = f4{0.f, 0.f, 0.f, 0.f};

#pragma unroll
  for (int tap = 0; tap < 9; ++tap) {
    int dy = tap / 3, dx = tap % 3;
    bfrag avhi[2], avlo[2];
#pragma unroll
    for (int mt = 0; mt < 2; ++mt) {
      avhi[mt] = *(const bfrag*)&wpb[((tap * 32) + mt * 16 + n) * 32 + quad * 8];
      avlo[mt] = *(const bfrag*)&wpb[(((9 + tap) * 32) + mt * 16 + n) * 32 + quad * 8];
    }
#pragma unroll
    for (int tu = 0; tu < 4; ++tu) {
      int t = wid + tu * 4;
      int r = t >> 2, g = t & 3;
      int pix = (r + dy) * 66 + g * 16 + n + dx;
      bfrag bhi = *(const bfrag*)&xl[pix * 32 + quad * 8];
      bfrag blo = *(const bfrag*)&xl[12672 + pix * 32 + quad * 8];
#pragma unroll
      for (int mt = 0; mt < 2; ++mt) {
        acc[tu][mt] = __builtin_amdgcn_mfma_f32_16x16x32_bf16(avhi[mt], bhi, acc[tu][mt], 0, 0, 0);
        acc[tu][mt] = __builtin_amdgcn_mfma_f32_16x16x32_bf16(avhi[mt], blo, acc[tu][mt], 0, 0, 0);
        acc[tu][mt] = __builtin_amdgcn_mfma_f32_16x16x32_bf16(avlo[mt], bhi, acc[tu][mt], 0, 0, 0);
      }
    }
  }

#pragma unroll
  for (int tu = 0; tu < 4; ++tu) {
    int t = wid + tu * 4;
    int r = t >> 2, g = t & 3;
    int gx = x0 + g * 16 + n, gy = y0 + r;
    size_t bpix = (size_t)b * HWP + (size_t)(gy + 1) * WP + (gx + 1);
#pragma unroll
    for (int mt = 0; mt < 2; ++mt) {
      int cob = mt * 16 + quad * 4;
      float v0 = fmaxf(acc[tu][mt][0] * scale[cob + 0] + bias[cob + 0], 0.f);
      float v1 = fmaxf(acc[tu][mt][1] * scale[cob + 1] + bias[cob + 1], 0.f);
      float v2 = fmaxf(acc[tu][mt][2] * scale[cob + 2] + bias[cob + 2], 0.f);
      float v3 = fmaxf(acc[tu][mt][3] * scale[cob + 3] + bias[cob + 3], 0.f);
      uint u0 = (uint)f2b(v0) | ((uint)f2b(v1) << 16);
      uint u1 = (uint)f2b(v2) | ((uint)f2b(v3) << 16);
      *(uint2*)&outp[bpix * 32 + cob] = uint2{u0, u1};
    }
  }
}

// ---------------------------------------------------------------------------
// BATCHED split-precision conv2 (all 3 w-chains in one dispatch):
// blockIdx.z = brIdx*2 + b with k7 mapped first (long blocks launch early).
// Compile-time nM=3 register structure; runtime nMb guards on fully-unrolled
// loops (wave-uniform branches, static acc indexing). Per-branch math is
// bit-identical to the verified convs2<nM> forms.
// ---------------------------------------------------------------------------
__global__ __launch_bounds__(256, 3)
void convs2z(const ushort* __restrict__ hP, const ushort* __restrict__ wp,
             const float* __restrict__ s3, const float* __restrict__ b3,
             const float* __restrict__ s5, const float* __restrict__ b5,
             const float* __restrict__ s7, const float* __restrict__ b7,
             ushort* __restrict__ w3o, ushort* __restrict__ w5o,
             ushort* __restrict__ w7o)
{
  __shared__ ushort xl[12672];

  const int tid = threadIdx.x;
  const int lane = tid & 63;
  const int wid = tid >> 6;
  const int x0 = blockIdx.x * 64, y0 = blockIdx.y * 4;
  const int zz = blockIdx.z;            // 0..5
  const int br = 2 - (zz >> 1);         // 2(k7),2,1(k5),1,0(k3),0
  const int b = zz & 1;

  int nMb, COb;
  const ushort* wpb;
  const float *scale, *bias;
  ushort* outw;
  if (br == 0)      { nMb = 1; COb = 8;  wpb = wp + PW2_K3; scale = s3; bias = b3; outw = w3o; }
  else if (br == 1) { nMb = 2; COb = 24; wpb = wp + PW2_K5; scale = s5; bias = b5; outw = w5o; }
  else              { nMb = 3; COb = 48; wpb = wp + PW2_K7; scale = s7; bias = b7; outw = w7o; }
  const int NM16 = nMb * 16;
  const ushort* hb = hP + ((size_t)br * 2 + b) * HWP * 32;

  for (int i = tid; i < 396 * 4; i += 256) {
    int oct = i & 3, rest = i >> 2;
    int xx = rest % 66, rr = rest / 66;
    *(uint4*)&xl[rest * 32 + oct * 8] =
        *(const uint4*)&hb[((size_t)(y0 + rr) * WP + (x0 + xx)) * 32 + oct * 8];
  }

  const int n = lane & 15, quad = lane >> 4;

  f4 acc[4][3];
#pragma unroll
  for (int tu = 0; tu < 4; ++tu)
#pragma unroll
    for (int mt = 0; mt < 3; ++mt) acc[tu][mt] = f4{0.f, 0.f, 0.f, 0.f};

  bfrag whi[2][3], wlo[2][3];
#pragma unroll
  for (int mt = 0; mt < 3; ++mt) {
    if (mt < nMb) {
      whi[0][mt] = *(const bfrag*)&wpb[(mt * 16 + n) * 32 + quad * 8];
      wlo[0][mt] = *(const bfrag*)&wpb[((9 * NM16) + mt * 16 + n) * 32 + quad * 8];
    }
  }
  __syncthreads();

#pragma unroll
  for (int tap = 0; tap < 9; ++tap) {
    const int dy = tap / 3, dx = tap % 3;
    const int cur = tap & 1, nxt = cur ^ 1;
    if (tap < 8) {
#pragma unroll
      for (int mt = 0; mt < 3; ++mt) {
        if (mt < nMb) {
          whi[nxt][mt] = *(const bfrag*)&wpb[(((tap + 1) * NM16) + mt * 16 + n) * 32 + quad * 8];
          wlo[nxt][mt] = *(const bfrag*)&wpb[(((9 + tap + 1) * NM16) + mt * 16 + n) * 32 + quad * 8];
        }
      }
    }
#pragma unroll
    for (int tu = 0; tu < 4; ++tu) {
      int t = wid + tu * 4;
      int r = t >> 2, g = t & 3;
      int pix = (r + dy) * 66 + g * 16 + n + dx;
      bfrag bv = *(const bfrag*)&xl[pix * 32 + quad * 8];
#pragma unroll
      for (int mt = 0; mt < 3; ++mt) {
        if (mt < nMb) {
          acc[tu][mt] = __builtin_amdgcn_mfma_f32_16x16x32_bf16(whi[cur][mt], bv, acc[tu][mt], 0, 0, 0);
          acc[tu][mt] = __builtin_amdgcn_mfma_f32_16x16x32_bf16(wlo[cur][mt], bv, acc[tu][mt], 0, 0, 0);
        }
      }
    }
  }

#pragma unroll
  for (int tu = 0; tu < 4; ++tu) {
    int t = wid + tu * 4;
    int r = t >> 2, g = t & 3;
    int gx = x0 + g * 16 + n, gy = y0 + r;
    size_t gpix = (size_t)gy * W_ + gx;

    float vs[3][4];
    float pa = 0.f;
#pragma unroll
    for (int mt = 0; mt < 3; ++mt)
#pragma unroll
      for (int rg = 0; rg < 4; ++rg) {
        int co = mt * 16 + quad * 4 + rg;
        float v = (mt < nMb && co < COb) ? acc[tu][mt][rg] * scale[co] + bias[co] : 0.f;
        vs[mt][rg] = v;
        pa += fabsf(v);
      }
    pa += __shfl_xor(pa, 16);
    pa += __shfl_xor(pa, 32);
    float inv = 1.f / (pa + EPS_);

    size_t base = ((size_t)b * HW + gpix) * (size_t)COb;
#pragma unroll
    for (int mt = 0; mt < 3; ++mt) {
      int cob = mt * 16 + quad * 4;
      if (mt < nMb && cob < COb) {
        uint u0 = (uint)f2b(vs[mt][0] * inv) | ((uint)f2b(vs[mt][1] * inv) << 16);
        uint u1 = (uint)f2b(vs[mt][2] * inv) | ((uint)f2b(vs[mt][3] * inv) << 16);
        *(uint2*)&outw[base + cob] = uint2{u0, u1};
      }
    }
  }
}

// ---------------------------------------------------------------------------
// BATCHED plain conv1 for mask+conf (R21, ran OK).
// ---------------------------------------------------------------------------
__global__ __launch_bounds__(256, 4)
void conv1pz(const float* __restrict__ xf, const ushort* __restrict__ wp,
             const float* __restrict__ sm, const float* __restrict__ bm,
             const float* __restrict__ sc, const float* __restrict__ bc,
             ushort* __restrict__ outh)
{
  __shared__ ushort xl[396 * 32];

  const int tid = threadIdx.x;
  const int lane = tid & 63;
  const int wid = tid >> 6;
  const int x0 = blockIdx.x * 64, y0 = blockIdx.y * 4;
  const int zz = blockIdx.z;            // 0..3
  const int br = zz >> 1, b = zz & 1;
  const ushort* wpb = wp + br * 9216;
  const float* scale = br ? sc : sm;
  const float* bias  = br ? bc : bm;
  ushort* outp = outh + (size_t)br * 2 * HWP * 32;

  for (int i = tid; i < 396 * 4; i += 256) {
    int oct = i & 3, rest = i >> 2;
    int xx = rest % 66, rr = rest / 66;
    int yy = y0 - 1 + rr, x = x0 - 1 + xx;
    uint4 v = {0, 0, 0, 0};
    if ((unsigned)yy < (unsigned)H_ && (unsigned)x < (unsigned)W_) {
      const float* src = xf + ((size_t)b * 32 + oct * 8) * HW + (size_t)yy * W_ + x;
      uint u[4];
#pragma unroll
      for (int j = 0; j < 4; ++j) {
        float a = src[(size_t)(2 * j + 0) * HW];
        float c = src[(size_t)(2 * j + 1) * HW];
        u[j] = (uint)f2b(a) | ((uint)f2b(c) << 16);
      }
      v = uint4{u[0], u[1], u[2], u[3]};
    }
    *(uint4*)&xl[rest * 32 + oct * 8] = v;
  }
  __syncthreads();

  const int n = lane & 15, quad = lane >> 4;

  f4 acc[4][2];
#pragma unroll
  for (int tu = 0; tu < 4; ++tu)
#pragma unroll
    for (int mt = 0; mt < 2; ++mt) acc[tu][mt] = f4{0.f, 0.f, 0.f, 0.f};

#pragma unroll
  for (int tap = 0; tap < 9; ++tap) {
    int dy = tap / 3, dx = tap % 3;
    bfrag av[2];
#pragma unroll
    for (int mt = 0; mt < 2; ++mt)
      av[mt] = *(const bfrag*)&wpb[((tap * 32) + mt * 16 + n) * 32 + quad * 8];
#pragma unroll
    for (int tu = 0; tu < 4; ++tu) {
      int t = wid + tu * 4;
      int r = t >> 2, g = t & 3;
      int pix = (r + dy) * 66 + g * 16 + n + dx;
      bfrag bv = *(const bfrag*)&xl[pix * 32 + quad * 8];
#pragma unroll
      for (int mt = 0; mt < 2; ++mt)
        acc[tu][mt] = __builtin_amdgcn_mfma_f32_16x16x32_bf16(av[mt], bv, acc[tu][mt], 0, 0, 0);
    }
  }

#pragma unroll
  for (int tu = 0; tu < 4; ++tu) {
    int t = wid + tu * 4;
    int r = t >> 2, g = t & 3;
    int gx = x0 + g * 16 + n, gy = y0 + r;
    size_t bpix = (size_t)b * HWP + (size_t)(gy + 1) * WP + (gx + 1);
#pragma unroll
    for (int mt = 0; mt < 2; ++mt) {
      int cob = mt * 16 + quad * 4;
      float v0 = fmaxf(acc[tu][mt][0] * scale[cob + 0] + bias[cob + 0], 0.f);
      float v1 = fmaxf(acc[tu][mt][1] * scale[cob + 1] + bias[cob + 1], 0.f);
      float v2 = fmaxf(acc[tu][mt][2] * scale[cob + 2] + bias[cob + 2], 0.f);
      float v3 = fmaxf(acc[tu][mt][3] * scale[cob + 3] + bias[cob + 3], 0.f);
      uint u0 = (uint)f2b(v0) | ((uint)f2b(v1) << 16);
      uint u1 = (uint)f2b(v2) | ((uint)f2b(v3) << 16);
      *(uint2*)&outp[bpix * 32 + cob] = uint2{u0, u1};
    }
  }
}

// ---------------------------------------------------------------------------
// Plain bf16 conv1 (t-branch, KB2=1) — R6 exact.
// ---------------------------------------------------------------------------
template<int KB2, int MINW>
__global__ __launch_bounds__(256, MINW)
void conv1p(const float* __restrict__ xf, const float* __restrict__ hnsp,
            const ushort* __restrict__ wp, const ushort* __restrict__ wp2,
            const float* __restrict__ scale, const float* __restrict__ bias,
            ushort* __restrict__ outh)
{
  __shared__ ushort xl[396 * 32];
  __shared__ ushort xl2[KB2 ? 396 * 8 : 8];

  const int tid = threadIdx.x;
  const int lane = tid & 63;
  const int wid = tid >> 6;
  const int x0 = blockIdx.x * 64, y0 = blockIdx.y * 4, b = blockIdx.z;

  if (KB2) {
    for (int i = tid; i < 396; i += 256) {
      int xx = i % 66, rr = i / 66;
      int yy = y0 - 1 + rr, x = x0 - 1 + xx;
      float v0 = 0.f, v1 = 0.f, v2 = 0.f;
      if ((unsigned)yy < (unsigned)H_ && (unsigned)x < (unsigned)W_) {
        size_t pix = (size_t)yy * W_ + x;
        v0 = hnsp[((size_t)b * 3 + 0) * HW + pix];
        v1 = hnsp[((size_t)b * 3 + 1) * HW + pix];
        v2 = hnsp[((size_t)b * 3 + 2) * HW + pix];
      }
      ushort h0b = f2b(v0), h1b = f2b(v1), h2b = f2b(v2);
      ushort l0 = f2b(v0 - b2f(h0b)), l1 = f2b(v1 - b2f(h1b)), l2 = f2b(v2 - b2f(h2b));
      uint u0 = (uint)h0b | ((uint)h1b << 16);
      uint u1 = (uint)h2b | ((uint)l0 << 16);
      uint u2 = (uint)l1 | ((uint)l2 << 16);
      *(uint4*)&xl2[i * 8] = uint4{u0, u1, u2, 0};
    }
  }
  for (int i = tid; i < 396 * 4; i += 256) {
    int oct = i & 3, rest = i >> 2;
    int xx = rest % 66, rr = rest / 66;
    int yy = y0 - 1 + rr, x = x0 - 1 + xx;
    uint4 v = {0, 0, 0, 0};
    if ((unsigned)yy < (unsigned)H_ && (unsigned)x < (unsigned)W_) {
      const float* src = xf + ((size_t)b * 32 + oct * 8) * HW + (size_t)yy * W_ + x;
      uint u[4];
#pragma unroll
      for (int j = 0; j < 4; ++j) {
        float a = src[(size_t)(2 * j + 0) * HW];
        float c = src[(size_t)(2 * j + 1) * HW];
        u[j] = (uint)f2b(a) | ((uint)f2b(c) << 16);
      }
      v = uint4{u[0], u[1], u[2], u[3]};
    }
    *(uint4*)&xl[rest * 32 + oct * 8] = v;
  }
  __syncthreads();

  const int n = lane & 15, quad = lane >> 4;

  f4 acc[4][2];
#pragma unroll
  for (int tu = 0; tu < 4; ++tu)
#pragma unroll
    for (int mt = 0; mt < 2; ++mt) acc[tu][mt] = f4{0.f, 0.f, 0.f, 0.f};

#pragma unroll
  for (int tap = 0; tap < 9; ++tap) {
    int dy = tap / 3, dx = tap % 3;
    bfrag av[2];
#pragma unroll
    for (int mt = 0; mt < 2; ++mt)
      av[mt] = *(const bfrag*)&wp[((tap * 32) + mt * 16 + n) * 32 + quad * 8];
    bfrag a2[KB2 ? 2 : 1];
    if (KB2) {
#pragma unroll
      for (int mt = 0; mt < 2; ++mt) {
        BU t; t.u = uint4{0, 0, 0, 0};
        if (lane < 16) t.f = *(const bfrag*)&wp2[(tap * 32 + mt * 16 + lane) * 8];
        a2[mt] = t.f;
      }
    }
#pragma unroll
    for (int tu = 0; tu < 4; ++tu) {
      int t = wid + tu * 4;
      int r = t >> 2, g = t & 3;
      int pix = (r + dy) * 66 + g * 16 + n + dx;
      bfrag bv = *(const bfrag*)&xl[pix * 32 + quad * 8];
#pragma unroll
      for (int mt = 0; mt < 2; ++mt)
        acc[tu][mt] = __builtin_amdgcn_mfma_f32_16x16x32_bf16(av[mt], bv, acc[tu][mt], 0, 0, 0);
      if (KB2) {
        BU t2; t2.u = uint4{0, 0, 0, 0};
        if (lane < 16) t2.f = *(const bfrag*)&xl2[pix * 8];
#pragma unroll
        for (int mt = 0; mt < 2; ++mt)
          acc[tu][mt] = __builtin_amdgcn_mfma_f32_16x16x32_bf16(a2[mt], t2.f, acc[tu][mt], 0, 0, 0);
      }
    }
  }

#pragma unroll
  for (int tu = 0; tu < 4; ++tu) {
    int t = wid + tu * 4;
    int r = t >> 2, g = t & 3;
    int gx = x0 + g * 16 + n, gy = y0 + r;
    size_t bpix = (size_t)b * HWP + (size_t)(gy + 1) * WP + (gx + 1);
#pragma unroll
    for (int mt = 0; mt < 2; ++mt) {
      int cob = mt * 16 + quad * 4;
      float v0 = fmaxf(acc[tu][mt][0] * scale[cob + 0] + bias[cob + 0], 0.f);
      float v1 = fmaxf(acc[tu][mt][1] * scale[cob + 1] + bias[cob + 1], 0.f);
      float v2 = fmaxf(acc[tu][mt][2] * scale[cob + 2] + bias[cob + 2], 0.f);
      float v3 = fmaxf(acc[tu][mt][3] * scale[cob + 3] + bias[cob + 3], 0.f);
      uint u0 = (uint)f2b(v0) | ((uint)f2b(v1) << 16);
      uint u1 = (uint)f2b(v2) | ((uint)f2b(v3) << 16);
      *(uint2*)&outh[bpix * 32 + cob] = uint2{u0, u1};
    }
  }
}

// ---------------------------------------------------------------------------
// BATCHED small conv2 for mask+conf (CO=3): blockIdx.z = br*2 + b.
// br=0 -> sigmoid*valid -> mask; br=1 -> softmax -> conf. Per-branch math
// identical to verified conv2g<2>/<3>; wave-uniform epilogue branch.
// ---------------------------------------------------------------------------
__global__ __launch_bounds__(256, 4)
void conv2gz(const ushort* __restrict__ hP, const ushort* __restrict__ wp,
             const float* __restrict__ mbias, const float* __restrict__ cbias,
             const float* __restrict__ h0, float* __restrict__ mask,
             float* __restrict__ conf)
{
  __shared__ ushort xl[12672];

  const int tid = threadIdx.x;
  const int lane = tid & 63;
  const int wid = tid >> 6;
  const int x0 = blockIdx.x * 64, y0 = blockIdx.y * 4;
  const int zz = blockIdx.z;            // 0..3
  const int br = zz >> 1, b = zz & 1;
  const int n = lane & 15, quad = lane >> 4;
  const ushort* wpb = wp + br * 4608;   // PG2_M / PG2_C
  const float* bias = br ? cbias : mbias;
  float* outf = br ? conf : mask;
  const ushort* hb = hP + ((size_t)br * 2 + b) * HWP * 32;

  for (int i = tid; i < 396 * 4; i += 256) {
    int oct = i & 3, rest = i >> 2;
    int xx = rest % 66, rr = rest / 66;
    *(uint4*)&xl[rest * 32 + oct * 8] =
        *(const uint4*)&hb[((size_t)(y0 + rr) * WP + (x0 + xx)) * 32 + oct * 8];
  }

  bfrag av[9];
#pragma unroll
  for (int tap = 0; tap < 9; ++tap)
    av[tap] = *(const bfrag*)&wpb[((tap * 16) + n) * 32 + quad * 8];

  f4 acc[4];
#pragma unroll
  for (int tu = 0; tu < 4; ++tu) acc[tu] = f4{0.f, 0.f, 0.f, 0.f};
  __syncthreads();

#pragma unroll
  for (int tap = 0; tap < 9; ++tap) {
    int dy = tap / 3, dx = tap % 3;
#pragma unroll
    for (int tu = 0; tu < 4; ++tu) {
      int t = wid + tu * 4;
      int r = t >> 2, g = t & 3;
      int pix = (r + dy) * 66 + g * 16 + n + dx;
      bfrag bv = *(const bfrag*)&xl[pix * 32 + quad * 8];
      acc[tu] = __builtin_amdgcn_mfma_f32_16x16x32_bf16(av[tap], bv, acc[tu], 0, 0, 0);
    }
  }

#pragma unroll
  for (int tu = 0; tu < 4; ++tu) {
    int t = wid + tu * 4;
    int r = t >> 2, g = t & 3;
    int gx = x0 + g * 16 + n, gy = y0 + r;
    size_t gpix = (size_t)gy * W_ + gx;
    size_t bpix = (size_t)b * HW + gpix;

    if (lane < 16) {
      if (br == 0) {
        float valid = (h0[bpix] > 0.001f) ? 1.f : 0.f;
#pragma unroll
        for (int rg = 0; rg < 3; ++rg) {
          float v = acc[tu][rg] + bias[rg];
          float sg = 1.f / (1.f + expf(-v));
          outf[((size_t)b * 3 + rg) * HW + gpix] = sg * valid;
        }
      } else {
        float v0 = acc[tu][0] + bias[0];
        float v1 = acc[tu][1] + bias[1];
        float v2 = acc[tu][2] + bias[2];
        float m = fmaxf(v0, fmaxf(v1, v2));
        float e0 = expf(v0 - m), e1 = expf(v1 - m), e2 = expf(v2 - m);
        float inv = 1.f / (e0 + e1 + e2);
        outf[((size_t)b * 3 + 0) * HW + gpix] = e0 * inv;
        outf[((size_t)b * 3 + 1) * HW + gpix] = e1 * inv;
        outf[((size_t)b * 3 + 2) * HW + gpix] = e2 * inv;
      }
    }
  }
}

// ---------------------------------------------------------------------------
// Small conv2 (CO=3), single-branch — used for the final temporal combine.
// ---------------------------------------------------------------------------
template<int EPI>
__global__ __launch_bounds__(256, 4)
void conv2g(const ushort* __restrict__ hP, const ushort* __restrict__ wp,
            const float* __restrict__ bias, const float* __restrict__ h0,
            const float* __restrict__ hnsp, float* __restrict__ outf)
{
  __shared__ ushort xl[12672];

  const int tid = threadIdx.x;
  const int lane = tid & 63;
  const int wid = tid >> 6;
  const int x0 = blockIdx.x * 64, y0 = blockIdx.y * 4, b = blockIdx.z;
  const int n = lane & 15, quad = lane >> 4;
  const ushort* hb = hP + (size_t)b * HWP * 32;

  for (int i = tid; i < 396 * 4; i += 256) {
    int oct = i & 3, rest = i >> 2;
    int xx = rest % 66, rr = rest / 66;
    *(uint4*)&xl[rest * 32 + oct * 8] =
        *(const uint4*)&hb[((size_t)(y0 + rr) * WP + (x0 + xx)) * 32 + oct * 8];
  }

  bfrag av[9];
#pragma unroll
  for (int tap = 0; tap < 9; ++tap)
    av[tap] = *(const bfrag*)&wp[((tap * 16) + n) * 32 + quad * 8];

  f4 acc[4];
#pragma unroll
  for (int tu = 0; tu < 4; ++tu) acc[tu] = f4{0.f, 0.f, 0.f, 0.f};
  __syncthreads();

#pragma unroll
  for (int tap = 0; tap < 9; ++tap) {
    int dy = tap / 3, dx = tap % 3;
#pragma unroll
    for (int tu = 0; tu < 4; ++tu) {
      int t = wid + tu * 4;
      int r = t >> 2, g = t & 3;
      int pix = (r + dy) * 66 + g * 16 + n + dx;
      bfrag bv = *(const bfrag*)&xl[pix * 32 + quad * 8];
      acc[tu] = __builtin_amdgcn_mfma_f32_16x16x32_bf16(av[tap], bv, acc[tu], 0, 0, 0);
    }
  }

#pragma unroll
  for (int tu = 0; tu < 4; ++tu) {
    int t = wid + tu * 4;
    int r = t >> 2, g = t & 3;
    int gx = x0 + g * 16 + n, gy = y0 + r;
    size_t gpix = (size_t)gy * W_ + gx;
    size_t bpix = (size_t)b * HW + gpix;

    if constexpr (EPI == 4) {
      if (lane < 16) {
        float v0 = acc[tu][0] + bias[0];
        float v1 = acc[tu][1] + bias[1];
        float v2 = acc[tu][2] + bias[2];
        float m = fmaxf(v0, fmaxf(v1, v2));
        float e0 = expf(v0 - m), e1 = expf(v1 - m), e2 = expf(v2 - m);
        float inv = 1.f / (e0 + e1 + e2);
        float a0 = hnsp[((size_t)b * 3 + 0) * HW + gpix];
        float a1 = hnsp[((size_t)b * 3 + 1) * HW + gpix];
        float a2v = hnsp[((size_t)b * 3 + 2) * HW + gpix];
        outf[bpix] = (e0 * a0 + e1 * a1 + e2 * a2v) * inv;
      }
    }
  }
}

// ---------------------------------------------------------------------------
__global__ __launch_bounds__(256)
void init_k(const float* __restrict__ hn, float* __restrict__ h3,
            float* __restrict__ h5, float* __restrict__ h7,
            float* __restrict__ hns)
{
  int t = blockIdx.x * 256 + threadIdx.x;
  if (t >= NP) return;
  float v = hn[t];
  h3[t] = v; h5[t] = v; h7[t] = v;
  int b = t / HW, rem = t - b * HW;
  hns[(size_t)b * 3 * HW + rem] = v;
}

// ---------------------------------------------------------------------------
// Propagation step — R6 exact.
// ---------------------------------------------------------------------------
__global__ __launch_bounds__(256)
void iterate_k(const float* __restrict__ h3i, const float* __restrict__ h5i,
               const float* __restrict__ h7i,
               float* __restrict__ h3o, float* __restrict__ h5o,
               float* __restrict__ h7o,
               const ushort* __restrict__ w3, const ushort* __restrict__ w5,
               const ushort* __restrict__ w7,
               const float* __restrict__ mask, const float* __restrict__ h0,
               float* __restrict__ hns, int chn, const float* __restrict__ conf)
{
  int t = blockIdx.x * 256 + threadIdx.x;
  if (t >= NP) return;
  int b = t / HW;
  int rem = t - b * HW;
  int y = rem / W_;
  int x = rem - y * W_;
  size_t pb = (size_t)b * HW;

  float h0v = h0[t];

  U8 a3; a3.u = *(const uint4*)&w3[((size_t)b * HW + rem) * 8];
  float s3 = 0.f, ws3 = 0.f;
#pragma unroll
  for (int p = 0; p < 8; ++p) {
    int tap = (p < 4) ? p : p + 1;
    int dy = tap / 3 - 1, dx = tap % 3 - 1;
    int yy = y + dy, xx = x + dx;
    float hv = ((unsigned)yy < (unsigned)H_ && (unsigned)xx < (unsigned)W_)
                   ? h3i[pb + yy * W_ + xx] : 0.f;
    float wv = b2f(a3.s[p]);
    ws3 += wv;
    s3 += wv * hv;
  }
  s3 += (1.f - ws3) * h3i[t];
  float m3 = mask[(size_t)(b * 3 + 0) * HW + rem];
  float n3 = (1.f - m3) * s3 + m3 * h0v;
  h3o[t] = n3;

  U8 a5[3];
  {
    const ushort* w5r = w5 + ((size_t)b * HW + rem) * 24;
#pragma unroll
    for (int q = 0; q < 3; ++q) a5[q].u = *(const uint4*)(w5r + q * 8);
  }
  float s5 = 0.f, ws5 = 0.f;
#pragma unroll
  for (int p = 0; p < 24; ++p) {
    int tap = (p < 12) ? p : p + 1;
    int dy = tap / 5 - 2, dx = tap % 5 - 2;
    int yy = y + dy, xx = x + dx;
    float hv = ((unsigned)yy < (unsigned)H_ && (unsigned)xx < (unsigned)W_)
                   ? h5i[pb + yy * W_ + xx] : 0.f;
    float wv = b2f(a5[p >> 3].s[p & 7]);
    ws5 += wv;
    s5 += wv * hv;
  }
  s5 += (1.f - ws5) * h5i[t];
  float m5 = mask[(size_t)(b * 3 + 1) * HW + rem];
  float n5 = (1.f - m5) * s5 + m5 * h0v;
  h5o[t] = n5;

  U8 a7[6];
  {
    const ushort* w7r = w7 + ((size_t)b * HW + rem) * 48;
#pragma unroll
    for (int q = 0; q < 6; ++q) a7[q].u = *(const uint4*)(w7r + q * 8);
  }
  float s7 = 0.f, ws7 = 0.f;
#pragma unroll
  for (int p = 0; p < 48; ++p) {
    int tap = (p < 24) ? p : p + 1;
    int dy = tap / 7 - 3, dx = tap % 7 - 3;
    int yy = y + dy, xx = x + dx;
    float hv = ((unsigned)yy < (unsigned)H_ && (unsigned)xx < (unsigned)W_)
                   ? h7i[pb + yy * W_ + xx] : 0.f;
    float wv = b2f(a7[p >> 3].s[p & 7]);
    ws7 += wv;
    s7 += wv * hv;
  }
  s7 += (1.f - ws7) * h7i[t];
  float m7 = mask[(size_t)(b * 3 + 2) * HW + rem];
  float n7 = (1.f - m7) * s7 + m7 * h0v;
  h7o[t] = n7;

  if (chn >= 0) {
    float c3 = conf[(size_t)(b * 3 + 0) * HW + rem];
    float c5 = conf[(size_t)(b * 3 + 1) * HW + rem];
    float c7 = conf[(size_t)(b * 3 + 2) * HW + rem];
    hns[(size_t)(b * 3 + chn) * HW + rem] = c3 * n3 + c5 * n5 + c7 * n7;
  }
}

extern "C" void kernel_launch(void* const* d_in, const int* in_sizes, int n_in,
                              void* d_out, int out_size, void* d_ws, size_t ws_size,
                              hipStream_t stream) {
  const float* fout = (const float*)d_in[0];
  const float* hn   = (const float*)d_in[1];
  const float* h0   = (const float*)d_in[2];
  const float* k3w1 = (const float*)d_in[3];
  const float* k3s1 = (const float*)d_in[4];
  const float* k3b1 = (const float*)d_in[5];
  const float* k3w2 = (const float*)d_in[6];
  const float* k3s2 = (const float*)d_in[7];
  const float* k3b2 = (const float*)d_in[8];
  const float* k5w1 = (const float*)d_in[9];
  const float* k5s1 = (const float*)d_in[10];
  const float* k5b1 = (const float*)d_in[11];
  const float* k5w2 = (const float*)d_in[12];
  const float* k5s2 = (const float*)d_in[13];
  const float* k5b2 = (const float*)d_in[14];
  const float* k7w1 = (const float*)d_in[15];
  const float* k7s1 = (const float*)d_in[16];
  const float* k7b1 = (const float*)d_in[17];
  const float* k7w2 = (const float*)d_in[18];
  const float* k7s2 = (const float*)d_in[19];
  const float* k7b2 = (const float*)d_in[20];
  const float* mw1  = (const float*)d_in[21];
  const float* ms1  = (const float*)d_in[22];
  const float* mb1  = (const float*)d_in[23];
  const float* mw2  = (const float*)d_in[24];
  const float* mbias2 = (const float*)d_in[25];
  const float* cw1  = (const float*)d_in[26];
  const float* cs1  = (const float*)d_in[27];
  const float* cb1  = (const float*)d_in[28];
  const float* cw2  = (const float*)d_in[29];
  const float* cbias2 = (const float*)d_in[30];
  const float* tw1  = (const float*)d_in[31];
  const float* ts1  = (const float*)d_in[32];
  const float* tb1  = (const float*)d_in[33];
  const float* tw2  = (const float*)d_in[34];
  const float* tbias2 = (const float*)d_in[35];

  float* out = (float*)d_out;

  // workspace: 3x hP plane-pairs + w planes bf16 + fp32 mask/conf/hA/hns + wprep
  size_t hP_elems = (size_t)2 * HWP * 32;            // ushorts per plane-pair
  size_t need = hP_elems * 3 * 2 + (size_t)NP * (80 * 2 + 15 * 4) + (size_t)PREP_N * 2;
  if (ws_size < need) return;
  ushort* hPb  = (ushort*)d_ws;            // 3 contiguous padded-NHWC bf16 plane-pairs
  ushort* w3   = hPb  + 3 * hP_elems;      // 8*NP  bf16 packed [B][HW][8]
  ushort* w5   = w3   + (size_t)8 * NP;    // 24*NP packed [B][HW][24]
  ushort* w7   = w5   + (size_t)24 * NP;   // 48*NP packed [B][HW][48]
  float* mask  = (float*)(w7 + (size_t)48 * NP);  // 3*NP f32
  float* conf  = mask + (size_t)3 * NP;    // 3*NP f32
  float* hA    = conf + (size_t)3 * NP;    // 6*NP f32 ping-pong
  float* hns   = hA   + (size_t)6 * NP;    // 3*NP f32
  ushort* wp   = (ushort*)(hns + (size_t)3 * NP); // PREP_N prepped weights

  dim3 blk(256);
  dim3 gc(W_ / 64, H_ / 4, B_);      // 19 x 64 x 2
  dim3 gc3(W_ / 64, H_ / 4, 6);      // batched: 3 branches x 2 batch
  dim3 gc2(W_ / 64, H_ / 4, 4);      // batched: 2 branches x 2 batch
  int ge = NP / 256;
  constexpr int PB = 2 * WP * 4 + 2 * (HP - 2) * 4;
  int gz = (6 * PB + 255) / 256;
  int gp = (PREP_N + 255) / 256;

  prep_k<<<gp, blk, 0, stream>>>(k3w1, k5w1, k7w1, k3w2, k5w2, k7w2,
                                 mw1, cw1, tw1, mw2, cw2, tw2, wp);
  zring_k<<<gz, blk, 0, stream>>>(hPb);

  // all 3 w-chain conv1s in ONE dispatch (per-branch hP planes)
  convs1z<<<gc3, blk, 0, stream>>>(fout, wp + PW1_K3,
                                   k3s1, k3b1, k5s1, k5b1, k7s1, k7b1, hPb);
  // all 3 w-chain conv2s in ONE dispatch (k7 blocks launch first)
  convs2z<<<gc3, blk, 0, stream>>>(hPb, wp,
                                   k3s2, k3b2, k5s2, k5b2, k7s2, k7b2,
                                   w3, w5, w7);

  // mask+conf conv1 in ONE dispatch (planes 0,1; after convs2z reads)
  conv1pz<<<gc2, blk, 0, stream>>>(fout, wp + PP1_M, ms1, mb1, cs1, cb1, hPb);
  // mask+conf conv2 in ONE dispatch
  conv2gz<<<gc2, blk, 0, stream>>>(hPb, wp + PG2_M, mbias2, cbias2, h0, mask, conf);

  // propagation
  float* h3c = hA + (size_t)0 * NP; float* h3n = hA + (size_t)1 * NP;
  float* h5c = hA + (size_t)2 * NP; float* h5n = hA + (size_t)3 * NP;
  float* h7c = hA + (size_t)4 * NP; float* h7n = hA + (size_t)5 * NP;

  init_k<<<ge, blk, 0, stream>>>(hn, h3c, h5c, h7c, hns);
  for (int i = 0; i < 6; ++i) {
    int chn = (i == 2) ? 1 : ((i == 5) ? 2 : -1);
    iterate_k<<<ge, blk, 0, stream>>>(h3c, h5c, h7c, h3n, h5n, h7n,
                                      w3, w5, w7, mask, h0, hns, chn, conf);
    float* t;
    t = h3c; h3c = h3n; h3n = t;
    t = h5c; h5c = h5n; h5n = t;
    t = h7c; h7c = h7n; h7n = t;
  }

  // final temporal-weight branch (plane 0, after conv2gz mask read it)
  conv1p<1, 3><<<gc, blk, 0, stream>>>(fout, hns, wp + PP1_T, wp + PP1T2, ts1, tb1, hPb);
  conv2g<4><<<gc, blk, 0, stream>>>(hPb, wp + PG2_T, tbias2, nullptr, hns, out);
}